// Round 12
// baseline (263.428 us; speedup 1.0000x reference)
//
#include <hip/hip_runtime.h>

typedef __attribute__((ext_vector_type(8))) short bf16x8;
typedef __attribute__((ext_vector_type(4))) float f32x4;
typedef __attribute__((ext_vector_type(8))) unsigned short u16x8;

#define MFMA16(a, b, c) __builtin_amdgcn_mfma_f32_16x16x32_bf16((a), (b), (c), 0, 0, 0)

static __device__ __forceinline__ unsigned short f2bf(float x) {
    union { float f; unsigned u; } v; v.f = x;
    unsigned r = v.u + 0x7fffu + ((v.u >> 16) & 1u);
    return (unsigned short)(r >> 16);
}

// async global->LDS, 16B per lane. LDS dest = wave base + lane*16 (linear).
static __device__ __forceinline__ void gload16(const void* g, void* l) {
    __builtin_amdgcn_global_load_lds(
        (const __attribute__((address_space(1))) unsigned int*)g,
        (__attribute__((address_space(3))) unsigned int*)l, 16, 0, 0);
}

// Balanced data-dependent tile assignment: XCD k = bid&7 gets active-tile range
// [T*k/8, T*(k+1)/8) (bijective chunked, m204). pc-fast => contiguous pr per XCD.
static __device__ __forceinline__ bool tile_assign(int bid, int apm, int npc_log2,
                                                   int& pr, int& pc) {
    const int k = bid & 7, j = bid >> 3;
    const int T = apm << npc_log2;
    const int lo = (T * k) >> 3, hi = (T * (k + 1)) >> 3;
    const int tix = lo + j;
    if (tix >= hi) return false;
    pc = tix & ((1 << npc_log2) - 1);
    pr = tix >> npc_log2;
    return true;
}

// ---------------- workspace layout (bytes) ----------------
#define WS_POOLED   0u          //  8,388,608  bf16 [4096][1024]
#define WS_LW1T     8388608u    //    262,144  bf16 [512][256]
#define WS_LW2T     8650752u    //  1,048,576  bf16 [1024][512]
#define WS_FWT      9699328u    //  1,048,576  bf16 [512][1024]
#define WS_SCAN     10747904u   //     16,640  int [4097]
#define WS_HEADER   10764544u   //        256  int: {M_c, M_cp}
#define WS_RMB      10764800u   //    409,600  int [102400]
#define WS_RMNEXT   11174400u   //    409,600  int [102400]
#define WS_HC       11584000u   // 26,214,400  bf16 [102400][128]
#define WS_SCRATCH  37798400u   // 33,554,432  f32 [4096][2][1024]
#define WS_HID      71352832u   // up to 104,857,600  bf16 [102400][512]

#define CB 4

// ================= fused prep: convert | scan | rowmap | corner =================
// bid 0..287   : weight transpose tiles (fp32 -> bf16 [N][K])
// bid 288      : global scan -> scanv/header (consumed by gemm1/gemm2/merge)
// bid 289..688 : rowmap + zeropad (self-derived scan; no cross-block dependency)
// bid 689..1712: corner MLP (self-derived prefix base; cw2 read direct from L1/L2)
__global__ __launch_bounds__(256) void prep_kernel(
    const float* __restrict__ lw1, const float* __restrict__ lw2, const float* __restrict__ fw,
    short* __restrict__ lw1t, short* __restrict__ lw2t, short* __restrict__ fwt,
    const int* __restrict__ nfpc, int* __restrict__ scanv, int* __restrict__ header,
    const float* __restrict__ fpoc,
    const float* __restrict__ cw1, const float* __restrict__ cb1,
    const float* __restrict__ cw2, const float* __restrict__ cb2,
    int* __restrict__ rm_b, int* __restrict__ rm_next,
    unsigned short* __restrict__ h_c)
{
    __shared__ __align__(16) char pmem[27776];
    const int bid = blockIdx.x;
    const int t = threadIdx.x;

    if (bid < 288) {
        // ---- weight transpose tile: dst[n][k] = src[k][n], lds[64][65] f32
        const float* src; short* dst;
        int srcN, nmax, dstK, n0, k0;
        if (bid < 32) {            // lw1t [512][256] <- lw1 [256][512]
            int tn = bid >> 2, tk = bid & 3;
            src = lw1; srcN = 512; nmax = 512; dst = lw1t; dstK = 256;
            n0 = tn * 64; k0 = tk * 64;
        } else if (bid < 160) {    // lw2t [1024][512] <- lw2 [512][1024]
            int u = bid - 32; int tn = u >> 3, tk = u & 7;
            src = lw2; srcN = 1024; nmax = 1024; dst = lw2t; dstK = 512;
            n0 = tn * 64; k0 = tk * 64;
        } else {                   // fwt [512][1024] <- fw [1024][511] (row 511 = 0)
            int u = bid - 160; int tn = u >> 4, tk = u & 15;
            src = fw; srcN = 511; nmax = 511; dst = fwt; dstK = 1024;
            n0 = tn * 64; k0 = tk * 64;
        }
        float* lds = (float*)pmem;      // 64*65*4 = 16640 B
        for (int e = t; e < 4096; e += 256) {
            int r = e >> 6, c = e & 63;
            int n = n0 + c;
            lds[r * 65 + c] = (n < nmax) ? src[(size_t)(k0 + r) * srcN + n] : 0.0f;
        }
        __syncthreads();
        for (int e = t; e < 1024; e += 256) {
            int rn = e >> 4, c4 = (e & 15) * 4;
            ushort4 o;
            o.x = f2bf(lds[(c4 + 0) * 65 + rn]);
            o.y = f2bf(lds[(c4 + 1) * 65 + rn]);
            o.z = f2bf(lds[(c4 + 2) * 65 + rn]);
            o.w = f2bf(lds[(c4 + 3) * 65 + rn]);
            *(ushort4*)&dst[(size_t)(n0 + rn) * dstK + k0 + c4] = o;
        }
        return;
    }

    if (bid == 288) {
        // ---- global exclusive prefix sum of nfpc[4096] -> scanv, header
        int* s = (int*)pmem;
        int loc[16]; int sum = 0;
        #pragma unroll
        for (int i = 0; i < 16; ++i) { loc[i] = sum; sum += nfpc[t * 16 + i]; }
        s[t] = sum;
        __syncthreads();
        for (int d = 1; d < 256; d <<= 1) {
            int v = (t >= d) ? s[t - d] : 0;
            __syncthreads();
            s[t] += v;
            __syncthreads();
        }
        int excl = (t == 0) ? 0 : s[t - 1];
        #pragma unroll
        for (int i = 0; i < 16; ++i) scanv[t * 16 + i] = excl + loc[i];
        if (t == 255) {
            int M = s[255];
            scanv[4096] = M;
            header[0] = M;
            header[1] = (M + 127) & ~127;
        }
        return;
    }

    if (bid < 689) {
        // ---- rowmap + zeropad, with self-derived full scan in LDS
        int* s_scan = (int*)pmem;                 // [4097] = 16388 B
        int* s_red  = (int*)(pmem + 16400);       // [256]
        int loc[16]; int sum = 0;
        #pragma unroll
        for (int i = 0; i < 16; ++i) { loc[i] = sum; sum += nfpc[t * 16 + i]; }
        s_red[t] = sum;
        __syncthreads();
        for (int d = 1; d < 256; d <<= 1) {
            int v = (t >= d) ? s_red[t - d] : 0;
            __syncthreads();
            s_red[t] += v;
            __syncthreads();
        }
        int excl = (t == 0) ? 0 : s_red[t - 1];
        #pragma unroll
        for (int i = 0; i < 16; ++i) s_scan[t * 16 + i] = excl + loc[i];
        if (t == 255) s_scan[4096] = s_red[255];
        __syncthreads();

        const int Mc = s_scan[4096];
        const int Mcp = (Mc + 127) & ~127;
        int r = (bid - 289) * 256 + t;            // covers 102400
        if (r >= 102400) return;
        if (r >= Mc) {
            rm_b[r] = -1; rm_next[r] = r;
            if (r < Mcp) {
                ushort4 z = {0, 0, 0, 0};
                #pragma unroll
                for (int j = 0; j < 128; j += 4)
                    *(ushort4*)&h_c[(size_t)r * 128 + j] = z;
            }
            return;
        }
        int lo = 0, hi = 4096;
        while (hi - lo > 1) { int mid = (lo + hi) >> 1; if (s_scan[mid] <= r) lo = mid; else hi = mid; }
        int b = lo, ii = r - s_scan[b], n = s_scan[b + 1] - s_scan[b];
        rm_b[r] = b;
        rm_next[r] = (ii + 1 == n) ? s_scan[b] : r + 1;
        return;
    }

    // ---- corner MLP block (cb = bid-689), self-derived prefix base
    {
        const int cb = bid - 689;
        const int b0 = cb * CB;
        float* s_h1 = (float*)pmem;               // CB*25*64*4 = 25600 B
        float* s_x  = (float*)(pmem + 25600);     // CB*50*4 = 800 B
        int* s_red  = (int*)(pmem + 26400);       // [256]
        int* s_off  = (int*)(pmem + 27424);       // [CB]
        int* s_nn   = (int*)(pmem + 27424 + CB * 4);

        // prefix base = sum(nfpc[0..b0))
        int partial = 0;
        const int c0 = t * 16;
        #pragma unroll
        for (int i = 0; i < 16; ++i) {
            int idx = c0 + i;
            partial += (idx < b0) ? nfpc[idx] : 0;
        }
        s_red[t] = partial;
        for (int e = t; e < CB * 50; e += 256) s_x[e] = fpoc[b0 * 50 + e];
        __syncthreads();
        for (int d = 128; d > 0; d >>= 1) {
            if (t < d) s_red[t] += s_red[t + d];
            __syncthreads();
        }
        if (t == 0) {
            int o = s_red[0];
            #pragma unroll
            for (int g = 0; g < CB; ++g) {
                s_off[g] = o;
                int nn = nfpc[b0 + g];
                s_nn[g] = nn;
                o += nn;
            }
        }
        __syncthreads();

        // layer 1: h1 = relu(x @ cw1 + cb1)
        for (int e = t; e < CB * 25 * 64; e += 256) {
            int i = e >> 6, j = e & 63;
            float v = s_x[i * 2] * cw1[j] + s_x[i * 2 + 1] * cw1[64 + j] + cb1[j];
            s_h1[e] = fmaxf(v, 0.f);
        }
        __syncthreads();

        // layer 2: float4 per thread, cw2 direct from L1/L2 (32 KB, resident)
        for (int e = t; e < CB * 25 * 32; e += 256) {
            int i = e >> 5, j4 = (e & 31) * 4;
            int g = i / 25, ii = i % 25;
            if (ii < s_nn[g]) {
                float4 a = *(const float4*)(cb2 + j4);
                const float* h1r = &s_h1[i * 64];
                #pragma unroll
                for (int k = 0; k < 64; ++k) {
                    float hv = h1r[k];
                    float4 wv = *(const float4*)(cw2 + k * 128 + j4);
                    a.x += hv * wv.x; a.y += hv * wv.y; a.z += hv * wv.z; a.w += hv * wv.w;
                }
                ushort4 o;
                o.x = f2bf(a.x); o.y = f2bf(a.y); o.z = f2bf(a.z); o.w = f2bf(a.w);
                *(ushort4*)&h_c[(size_t)(s_off[g] + ii) * 128 + j4] = o;
            }
        }
    }
}

// ---------------- gemm1: pair(gathered from h_c) @ lw1t^T -> relu+lb1 -> hid ----------
// R8 config: BK=64, 33.8KB LDS, (256,4) — measured local optimum.
__global__ __launch_bounds__(256, 4) void gemm1_kernel(
    const unsigned short* __restrict__ h_c,   // [M_cp][128]
    const short* __restrict__ lw1t,           // [512][256]
    const float* __restrict__ lb1,
    const int* __restrict__ rm_next,
    const int* __restrict__ header,
    unsigned short* __restrict__ hid,         // [crows][512] chunk-local
    int row0, int pm)
{
    __shared__ __align__(16) char smem[33280];   // K-loop: A(16K)+B(16K); epilogue: f32[64][130]
    __shared__ int s_next[128];

    const int Mcp = header[1];
    int rem = Mcp - row0;
    int apm = (rem <= 0) ? 0 : min(pm, (rem + 127) >> 7);
    int pr, pc;
    if (!tile_assign(blockIdx.x, apm, 2, pr, pc)) return;
    const int Rl = pr * 128;                          // chunk-local
    const int R = row0 + Rl;                          // global compact row base

    const int t = threadIdx.x;
    const int w = t >> 6, l = t & 63, q = l >> 4, ln = l & 15;
    const int wr = w >> 1, wc = w & 1;
    char* ldsA = smem;
    char* ldsB = smem + 16384;

    if (t < 128) s_next[t] = rm_next[R + t];
    __syncthreads();

    f32x4 acc[4][4];
    #pragma unroll
    for (int m = 0; m < 4; ++m)
        #pragma unroll
        for (int n = 0; n < 4; ++n) acc[m][n] = 0;

    #pragma unroll
    for (int kt = 0; kt < 4; ++kt) {
        const int k0 = kt * 64;
        // ---- stage A: gather pair rows (pre-swizzled source)
        #pragma unroll
        for (int i = 0; i < 4; ++i) {
            int o = i * 4096 + t * 16;
            int row = o >> 7, colb = o & 127;
            int colb2 = colb ^ ((row & 7) << 4);
            int k = k0 + (colb2 >> 1);                // 0..255 (compile-time half per kt)
            int srow, kk2;
            if (k < 128) { srow = R + row; kk2 = k; }
            else { srow = s_next[row]; kk2 = k - 128; }
            gload16(h_c + (size_t)srow * 128 + kk2, ldsA + o);
        }
        // ---- stage B from lw1t
        #pragma unroll
        for (int i = 0; i < 4; ++i) {
            int o = i * 4096 + t * 16;
            int row = o >> 7, colb = o & 127;
            int colb2 = colb ^ ((row & 7) << 4);
            gload16(lw1t + (size_t)(pc * 128 + row) * 256 + k0 + (colb2 >> 1), ldsB + o);
        }
        asm volatile("s_waitcnt vmcnt(0)");
        __syncthreads();
        #pragma unroll
        for (int kk = 0; kk < 2; ++kk) {
            bf16x8 af[4], bf[4];
            #pragma unroll
            for (int m = 0; m < 4; ++m) {
                int row = wr * 64 + m * 16 + ln;
                int off = (row * 128 + kk * 64 + q * 16) ^ ((row & 7) << 4);
                af[m] = *(const bf16x8*)(ldsA + off);
            }
            #pragma unroll
            for (int n = 0; n < 4; ++n) {
                int row = wc * 64 + n * 16 + ln;
                int off = (row * 128 + kk * 64 + q * 16) ^ ((row & 7) << 4);
                bf[n] = *(const bf16x8*)(ldsB + off);
            }
            #pragma unroll
            for (int m = 0; m < 4; ++m)
                #pragma unroll
                for (int n = 0; n < 4; ++n)
                    acc[m][n] = MFMA16(af[m], bf[n], acc[m][n]);
        }
        __syncthreads();
    }

    // ---- epilogue: relu+bias -> stage 64-row halves to LDS f32 -> vectorized bf16 write.
    float* s_f32 = (float*)smem;        // [64][130]
    const int erow = t >> 2;            // 0..63
    const int ecl = (t & 3) * 8;        // col base; +j*32 per store
    #pragma unroll 1
    for (int h = 0; h < 2; ++h) {
        if (wr == h) {
            #pragma unroll
            for (int n = 0; n < 4; ++n) {
                int col = wc * 64 + n * 16 + ln;          // tile-local
                float bias = lb1[pc * 128 + col];
                #pragma unroll
                for (int m = 0; m < 4; ++m)
                    #pragma unroll
                    for (int r = 0; r < 4; ++r)
                        s_f32[(m * 16 + q * 4 + r) * 130 + col] =
                            fmaxf(acc[m][n][r] + bias, 0.f);
            }
        }
        __syncthreads();
        {
            const size_t gr = (size_t)(Rl + h * 64 + erow) * 512 + pc * 128;
            #pragma unroll
            for (int j = 0; j < 4; ++j) {
                int c0 = ecl + j * 32;
                float4 a = *(const float4*)&s_f32[erow * 130 + c0];
                float4 b = *(const float4*)&s_f32[erow * 130 + c0 + 4];
                u16x8 o;
                o[0] = f2bf(a.x); o[1] = f2bf(a.y); o[2] = f2bf(a.z); o[3] = f2bf(a.w);
                o[4] = f2bf(b.x); o[5] = f2bf(b.y); o[6] = f2bf(b.z); o[7] = f2bf(b.w);
                *(u16x8*)&hid[gr + c0] = o;
            }
        }
        __syncthreads();
    }
}

// ---------------- gemm2: hid @ lw2t^T + segmented maxpool -> scratch partials ----------
// R8 config: BK=64, 33.8KB LDS, (256,4).
__global__ __launch_bounds__(256, 4) void gemm2_kernel(
    const unsigned short* __restrict__ hid,   // [crows][512] chunk-local
    const short* __restrict__ lw2t,           // [1024][512]
    const int* __restrict__ rm_b,
    const int* __restrict__ scanv,
    const int* __restrict__ header,
    float* __restrict__ scratch,              // [4096][2][1024] f32
    int row0, int pm)
{
    __shared__ __align__(16) char smem[33280];   // K-loop: A(16K)+B(16K); epilogue: f32[64][130]
    __shared__ int s_batch[128];

    const int Mcp = header[1];
    int rem = Mcp - row0;
    int apm = (rem <= 0) ? 0 : min(pm, (rem + 127) >> 7);
    int pr, pc;
    if (!tile_assign(blockIdx.x, apm, 3, pr, pc)) return;
    const int Rl = pr * 128;
    const int R = row0 + Rl;

    const int t = threadIdx.x;
    const int w = t >> 6, l = t & 63, q = l >> 4, ln = l & 15;
    const int wr = w >> 1, wc = w & 1;
    char* ldsA = smem;
    char* ldsB = smem + 16384;

    if (t < 128) s_batch[t] = rm_b[R + t];
    __syncthreads();

    f32x4 acc[4][4];
    #pragma unroll
    for (int m = 0; m < 4; ++m)
        #pragma unroll
        for (int n = 0; n < 4; ++n) acc[m][n] = 0;

    for (int kt = 0; kt < 8; ++kt) {
        const int k0 = kt * 64;
        #pragma unroll
        for (int i = 0; i < 4; ++i) {
            int o = i * 4096 + t * 16;
            int row = o >> 7, colb = o & 127;
            int colb2 = colb ^ ((row & 7) << 4);
            gload16(hid + (size_t)(Rl + row) * 512 + k0 + (colb2 >> 1), ldsA + o);
        }
        #pragma unroll
        for (int i = 0; i < 4; ++i) {
            int o = i * 4096 + t * 16;
            int row = o >> 7, colb = o & 127;
            int colb2 = colb ^ ((row & 7) << 4);
            gload16(lw2t + (size_t)(pc * 128 + row) * 512 + k0 + (colb2 >> 1), ldsB + o);
        }
        asm volatile("s_waitcnt vmcnt(0)");
        __syncthreads();
        #pragma unroll
        for (int kk = 0; kk < 2; ++kk) {
            bf16x8 af[4], bf[4];
            #pragma unroll
            for (int m = 0; m < 4; ++m) {
                int row = wr * 64 + m * 16 + ln;
                int off = (row * 128 + kk * 64 + q * 16) ^ ((row & 7) << 4);
                af[m] = *(const bf16x8*)(ldsA + off);
            }
            #pragma unroll
            for (int n = 0; n < 4; ++n) {
                int row = wc * 64 + n * 16 + ln;
                int off = (row * 128 + kk * 64 + q * 16) ^ ((row & 7) << 4);
                bf[n] = *(const bf16x8*)(ldsB + off);
            }
            #pragma unroll
            for (int m = 0; m < 4; ++m)
                #pragma unroll
                for (int n = 0; n < 4; ++n)
                    acc[m][n] = MFMA16(af[m], bf[n], acc[m][n]);
        }
        __syncthreads();
    }

    // ---- segmented maxpool epilogue: stage 64-row halves, walk 32-row units.
    // A batch (n<=25<32) spans at most 2 consecutive 32-row units ->
    // slot = (batch started before this unit) ? 1 : 0.
    // s_f32 holds only the current 64-row HALF: index half-local (esub*32+row).
    float* s_f32 = (float*)smem;    // [64][130] f32
    const int ecol = t & 127, esub = t >> 7;     // 256 threads: 128 cols x 2 units
    #pragma unroll 1
    for (int h = 0; h < 2; ++h) {
        if (wr == h) {
            #pragma unroll
            for (int m = 0; m < 4; ++m)
                #pragma unroll
                for (int n = 0; n < 4; ++n)
                    #pragma unroll
                    for (int r = 0; r < 4; ++r)
                        s_f32[(m * 16 + q * 4 + r) * 130 + wc * 64 + n * 16 + ln] = acc[m][n][r];
        }
        __syncthreads();
        {
            const int ub = R + h * 64 + esub * 32;   // unit base (global row)
            const int rb = h * 64 + esub * 32;       // tile-local base (s_batch index)
            const int lb = esub * 32;                // half-local base (s_f32 index)
            int curb = s_batch[rb];
            float curmax = s_f32[lb * 130 + ecol];
            #pragma unroll 8
            for (int row = 1; row < 32; ++row) {
                int b = s_batch[rb + row];
                float v = s_f32[(lb + row) * 130 + ecol];
                if (b == curb) {
                    curmax = fmaxf(curmax, v);
                } else {
                    if (curb >= 0) {
                        int slot = (scanv[curb] < ub) ? 1 : 0;
                        scratch[((size_t)curb * 2 + slot) * 1024 + pc * 128 + ecol] = curmax;
                    }
                    curb = b;
                    curmax = v;
                }
            }
            if (curb >= 0) {
                int slot = (scanv[curb] < ub) ? 1 : 0;
                scratch[((size_t)curb * 2 + slot) * 1024 + pc * 128 + ecol] = curmax;
            }
        }
        __syncthreads();
    }
}

// ---------------- merge: max of <=2 partials + lb2 -> pooled bf16 ----------------
__global__ void merge_kernel(const float* __restrict__ scratch, const int* __restrict__ scanv,
                             const float* __restrict__ lb2, unsigned short* __restrict__ pooled_b)
{
    const int b = blockIdx.x;                 // 4096 blocks; thread t does cols 4t..4t+3
    const int col4 = threadIdx.x * 4;
    const int o0 = scanv[b], o1 = scanv[b + 1];
    const bool spans = (o0 >> 5) != ((o1 - 1) >> 5);    // 32-row units
    float4 v = *(const float4*)&scratch[((size_t)b * 2) * 1024 + col4];
    if (spans) {
        float4 u = *(const float4*)&scratch[((size_t)b * 2 + 1) * 1024 + col4];
        v.x = fmaxf(v.x, u.x); v.y = fmaxf(v.y, u.y);
        v.z = fmaxf(v.z, u.z); v.w = fmaxf(v.w, u.w);
    }
    float4 bb = *(const float4*)(lb2 + col4);
    ushort4 o;
    o.x = f2bf(v.x + bb.x); o.y = f2bf(v.y + bb.y);
    o.z = f2bf(v.z + bb.z); o.w = f2bf(v.w + bb.w);
    *(ushort4*)&pooled_b[(size_t)b * 1024 + col4] = o;
}

// ---------------- final: pooled[4096,1024] @ fw[1024,511] + fb ----------------
// BN=128 per block (grid y=4): halves redundant pooled re-reads vs BN=64.
__global__ __launch_bounds__(512, 2) void final_kernel(
    const unsigned short* __restrict__ pooled_b,
    const short* __restrict__ fwt,    // bf16 [512][1024]
    const float* __restrict__ fb,
    float* __restrict__ out)
{
    const int tid = threadIdx.x;
    const int w = tid >> 6, l = tid & 63, q = l >> 4, ln = l & 15;
    const int rb = blockIdx.x * 128 + w * 16;
    const int nb0 = blockIdx.y * 128;

    f32x4 acc[8];
    #pragma unroll
    for (int j = 0; j < 8; ++j) acc[j] = 0;

    const short* pb = (const short*)pooled_b;
    #pragma unroll 2
    for (int ks = 0; ks < 32; ++ks) {
        bf16x8 a = *(const bf16x8*)(pb + (rb + ln) * 1024 + ks * 32 + q * 8);
        #pragma unroll
        for (int j = 0; j < 8; ++j) {
            bf16x8 bf = *(const bf16x8*)(fwt + (nb0 + j * 16 + ln) * 1024 + ks * 32 + q * 8);
            acc[j] = MFMA16(a, bf, acc[j]);
        }
    }
    #pragma unroll
    for (int j = 0; j < 8; ++j) {
        int col = nb0 + j * 16 + ln;
        if (col < 511) {
            float bias = fb[col];
            #pragma unroll
            for (int r = 0; r < 4; ++r) {
                int row = rb + q * 4 + r;
                out[row * 511 + col] = acc[j][r] + bias;
            }
        }
    }
}

extern "C" void kernel_launch(void* const* d_in, const int* in_sizes, int n_in,
                              void* d_out, int out_size, void* d_ws, size_t ws_size,
                              hipStream_t stream)
{
    const float* fpoc = (const float*)d_in[0];
    const float* cw1  = (const float*)d_in[1];
    const float* cb1  = (const float*)d_in[2];
    const float* cw2  = (const float*)d_in[3];
    const float* cb2  = (const float*)d_in[4];
    const float* lw1  = (const float*)d_in[5];
    const float* lb1  = (const float*)d_in[6];
    const float* lw2  = (const float*)d_in[7];
    const float* lb2  = (const float*)d_in[8];
    const float* fw   = (const float*)d_in[9];
    const float* fb   = (const float*)d_in[10];
    const int*  nfpc  = (const int*)d_in[11];

    char* ws = (char*)d_ws;
    unsigned short* pooled_b = (unsigned short*)(ws + WS_POOLED);
    short* lw1t   = (short*)(ws + WS_LW1T);
    short* lw2t   = (short*)(ws + WS_LW2T);
    short* fwt    = (short*)(ws + WS_FWT);
    int*   scanv  = (int*)(ws + WS_SCAN);
    int*   header = (int*)(ws + WS_HEADER);
    int*   rm_b   = (int*)(ws + WS_RMB);
    int*   rm_next= (int*)(ws + WS_RMNEXT);
    unsigned short* h_c = (unsigned short*)(ws + WS_HC);
    float* scratch = (float*)(ws + WS_SCRATCH);
    unsigned short* hid = (unsigned short*)(ws + WS_HID);

    // adaptive chunking of hid (worst case 102400 rows x 512 x bf16 = 100 MB)
    size_t avail = (ws_size > WS_HID) ? ws_size - WS_HID : 0;
    int n_chunks = 1;
    while (n_chunks < 16 && (size_t)(104857600u / n_chunks) > avail) n_chunks <<= 1;
    const int crows = 102400 / n_chunks;
    const int pm = crows / 128;

    hipLaunchKernelGGL(prep_kernel, dim3(1713), dim3(256), 0, stream,
                       lw1, lw2, fw, lw1t, lw2t, fwt, nfpc, scanv, header,
                       fpoc, cw1, cb1, cw2, cb2, rm_b, rm_next, h_c);
    const int g1 = ((pm * 4 + 7) / 8) * 8;   // grid covers worst-case per-XCD share
    const int g2 = pm * 8;
    for (int c = 0; c < n_chunks; ++c) {
        int row0 = c * crows;
        hipLaunchKernelGGL(gemm1_kernel, dim3(g1), dim3(256), 0, stream,
                           h_c, lw1t, lb1, rm_next, header, hid, row0, pm);
        hipLaunchKernelGGL(gemm2_kernel, dim3(g2), dim3(256), 0, stream,
                           hid, lw2t, rm_b, scanv, header, scratch, row0, pm);
    }
    hipLaunchKernelGGL(merge_kernel, dim3(4096), dim3(256), 0, stream,
                       scratch, scanv, lb2, pooled_b);
    hipLaunchKernelGGL(final_kernel, dim3(32, 4), dim3(512), 0, stream,
                       pooled_b, fwt, fb, (float*)d_out);
}

// Round 13
// 231.200 us; speedup vs baseline: 1.1394x; 1.1394x over previous
//
#include <hip/hip_runtime.h>

typedef __attribute__((ext_vector_type(8))) short bf16x8;
typedef __attribute__((ext_vector_type(4))) float f32x4;
typedef __attribute__((ext_vector_type(8))) unsigned short u16x8;

#define MFMA16(a, b, c) __builtin_amdgcn_mfma_f32_16x16x32_bf16((a), (b), (c), 0, 0, 0)

static __device__ __forceinline__ unsigned short f2bf(float x) {
    union { float f; unsigned u; } v; v.f = x;
    unsigned r = v.u + 0x7fffu + ((v.u >> 16) & 1u);
    return (unsigned short)(r >> 16);
}

// async global->LDS, 16B per lane. LDS dest = wave base + lane*16 (linear).
static __device__ __forceinline__ void gload16(const void* g, void* l) {
    __builtin_amdgcn_global_load_lds(
        (const __attribute__((address_space(1))) unsigned int*)g,
        (__attribute__((address_space(3))) unsigned int*)l, 16, 0, 0);
}

// Balanced data-dependent tile assignment: XCD k = bid&7 gets active-tile range
// [T*k/8, T*(k+1)/8) (bijective chunked, m204). pc-fast => contiguous pr per XCD.
static __device__ __forceinline__ bool tile_assign(int bid, int apm, int npc_log2,
                                                   int& pr, int& pc) {
    const int k = bid & 7, j = bid >> 3;
    const int T = apm << npc_log2;
    const int lo = (T * k) >> 3, hi = (T * (k + 1)) >> 3;
    const int tix = lo + j;
    if (tix >= hi) return false;
    pc = tix & ((1 << npc_log2) - 1);
    pr = tix >> npc_log2;
    return true;
}

// ---------------- workspace layout (bytes) ----------------
#define WS_POOLED   0u          //  8,388,608  bf16 [4096][1024]
#define WS_LW1T     8388608u    //    262,144  bf16 [512][256]
#define WS_LW2T     8650752u    //  1,048,576  bf16 [1024][512]
#define WS_FWT      9699328u    //  1,048,576  bf16 [512][1024]
#define WS_SCAN     10747904u   //     16,640  int [4097]
#define WS_HEADER   10764544u   //        256  int: {M_c, M_cp}
#define WS_RMB      10764800u   //    409,600  int [102400]
#define WS_RMNEXT   11174400u   //    409,600  int [102400]
#define WS_HC       11584000u   // 26,214,400  bf16 [102400][128]
#define WS_SCRATCH  37798400u   // 33,554,432  f32 [4096][2][1024]
#define WS_HID      71352832u   // up to 104,857,600  bf16 [102400][512]

#define CB 4

// ================= prep: convert | scan | rowmap (no corner — L1-BW trap, R12) ====
// bid 0..287   : weight transpose tiles (fp32 -> bf16 [N][K]), lds[64][65]
// bid 288      : global scan -> scanv/header (consumed by corner/gemms/merge)
// bid 289..688 : rowmap + zeropad (self-derived scan; runs concurrently)
__global__ __launch_bounds__(256) void prep_kernel(
    const float* __restrict__ lw1, const float* __restrict__ lw2, const float* __restrict__ fw,
    short* __restrict__ lw1t, short* __restrict__ lw2t, short* __restrict__ fwt,
    const int* __restrict__ nfpc, int* __restrict__ scanv, int* __restrict__ header,
    int* __restrict__ rm_b, int* __restrict__ rm_next,
    unsigned short* __restrict__ h_c)
{
    __shared__ __align__(16) char pmem[17424];
    const int bid = blockIdx.x;
    const int t = threadIdx.x;

    if (bid < 288) {
        // ---- weight transpose tile: dst[n][k] = src[k][n]
        const float* src; short* dst;
        int srcN, nmax, dstK, n0, k0;
        if (bid < 32) {            // lw1t [512][256] <- lw1 [256][512]
            int tn = bid >> 2, tk = bid & 3;
            src = lw1; srcN = 512; nmax = 512; dst = lw1t; dstK = 256;
            n0 = tn * 64; k0 = tk * 64;
        } else if (bid < 160) {    // lw2t [1024][512] <- lw2 [512][1024]
            int u = bid - 32; int tn = u >> 3, tk = u & 7;
            src = lw2; srcN = 1024; nmax = 1024; dst = lw2t; dstK = 512;
            n0 = tn * 64; k0 = tk * 64;
        } else {                   // fwt [512][1024] <- fw [1024][511] (row 511 = 0)
            int u = bid - 160; int tn = u >> 4, tk = u & 15;
            src = fw; srcN = 511; nmax = 511; dst = fwt; dstK = 1024;
            n0 = tn * 64; k0 = tk * 64;
        }
        float* lds = (float*)pmem;      // 64*65*4 = 16640 B
        for (int e = t; e < 4096; e += 256) {
            int r = e >> 6, c = e & 63;
            int n = n0 + c;
            lds[r * 65 + c] = (n < nmax) ? src[(size_t)(k0 + r) * srcN + n] : 0.0f;
        }
        __syncthreads();
        for (int e = t; e < 1024; e += 256) {
            int rn = e >> 4, c4 = (e & 15) * 4;
            ushort4 o;
            o.x = f2bf(lds[(c4 + 0) * 65 + rn]);
            o.y = f2bf(lds[(c4 + 1) * 65 + rn]);
            o.z = f2bf(lds[(c4 + 2) * 65 + rn]);
            o.w = f2bf(lds[(c4 + 3) * 65 + rn]);
            *(ushort4*)&dst[(size_t)(n0 + rn) * dstK + k0 + c4] = o;
        }
        return;
    }

    if (bid == 288) {
        // ---- global exclusive prefix sum of nfpc[4096] -> scanv, header
        int* s = (int*)pmem;
        int loc[16]; int sum = 0;
        #pragma unroll
        for (int i = 0; i < 16; ++i) { loc[i] = sum; sum += nfpc[t * 16 + i]; }
        s[t] = sum;
        __syncthreads();
        for (int d = 1; d < 256; d <<= 1) {
            int v = (t >= d) ? s[t - d] : 0;
            __syncthreads();
            s[t] += v;
            __syncthreads();
        }
        int excl = (t == 0) ? 0 : s[t - 1];
        #pragma unroll
        for (int i = 0; i < 16; ++i) scanv[t * 16 + i] = excl + loc[i];
        if (t == 255) {
            int M = s[255];
            scanv[4096] = M;
            header[0] = M;
            header[1] = (M + 127) & ~127;
        }
        return;
    }

    // ---- rowmap + zeropad, self-derived full scan in LDS (validated R12)
    {
        int* s_scan = (int*)pmem;                 // [4097] = 16388 B
        int* s_red  = (int*)(pmem + 16400);       // [256]
        int loc[16]; int sum = 0;
        #pragma unroll
        for (int i = 0; i < 16; ++i) { loc[i] = sum; sum += nfpc[t * 16 + i]; }
        s_red[t] = sum;
        __syncthreads();
        for (int d = 1; d < 256; d <<= 1) {
            int v = (t >= d) ? s_red[t - d] : 0;
            __syncthreads();
            s_red[t] += v;
            __syncthreads();
        }
        int excl = (t == 0) ? 0 : s_red[t - 1];
        #pragma unroll
        for (int i = 0; i < 16; ++i) s_scan[t * 16 + i] = excl + loc[i];
        if (t == 255) s_scan[4096] = s_red[255];
        __syncthreads();

        const int Mc = s_scan[4096];
        const int Mcp = (Mc + 127) & ~127;
        int r = (bid - 289) * 256 + t;            // covers 102400
        if (r >= 102400) return;
        if (r >= Mc) {
            rm_b[r] = -1; rm_next[r] = r;
            if (r < Mcp) {
                ushort4 z = {0, 0, 0, 0};
                #pragma unroll
                for (int j = 0; j < 128; j += 4)
                    *(ushort4*)&h_c[(size_t)r * 128 + j] = z;
            }
            return;
        }
        int lo = 0, hi = 4096;
        while (hi - lo > 1) { int mid = (lo + hi) >> 1; if (s_scan[mid] <= r) lo = mid; else hi = mid; }
        int b = lo, ii = r - s_scan[b], n = s_scan[b + 1] - s_scan[b];
        rm_b[r] = b;
        rm_next[r] = (ii + 1 == n) ? s_scan[b] : r + 1;
    }
}

// ---------------- corner MLP -> compacted h_c bf16 [M_c][128] ----------------
// R11-proven form: cw2 staged in LDS (157 TB/s path — NOT direct L1, see R12).
__global__ __launch_bounds__(256, 2) void corner_kernel(
    const float* __restrict__ fpoc,
    const float* __restrict__ cw1, const float* __restrict__ cb1,
    const float* __restrict__ cw2, const float* __restrict__ cb2,
    const int* __restrict__ scanv,
    unsigned short* __restrict__ h_c)
{
    __shared__ float s_h1[CB * 25 * 64];
    __shared__ float s_cw2[64 * 128];
    __shared__ float s_x[CB * 25 * 2];
    __shared__ int s_off[CB], s_nn[CB];
    const int b0 = blockIdx.x * CB;
    const int t = threadIdx.x;

    for (int e = t; e < 64 * 128; e += 256) s_cw2[e] = cw2[e];
    for (int e = t; e < CB * 50; e += 256) s_x[e] = fpoc[b0 * 50 + e];
    if (t < CB) { int o = scanv[b0 + t]; s_off[t] = o; s_nn[t] = scanv[b0 + t + 1] - o; }
    __syncthreads();

    for (int e = t; e < CB * 25 * 64; e += 256) {
        int i = e >> 6, j = e & 63;
        float v = s_x[i * 2] * cw1[j] + s_x[i * 2 + 1] * cw1[64 + j] + cb1[j];
        s_h1[e] = fmaxf(v, 0.f);
    }
    __syncthreads();

    // layer 2: float4 per thread (ds_read_b128 on cw2)
    for (int e = t; e < CB * 25 * 32; e += 256) {
        int i = e >> 5, j4 = (e & 31) * 4;
        int g = i / 25, ii = i % 25;
        if (ii < s_nn[g]) {
            float4 a = *(const float4*)(cb2 + j4);
            const float* h1r = &s_h1[i * 64];
            #pragma unroll
            for (int k = 0; k < 64; ++k) {
                float hv = h1r[k];
                float4 wv = *(const float4*)(s_cw2 + k * 128 + j4);
                a.x += hv * wv.x; a.y += hv * wv.y; a.z += hv * wv.z; a.w += hv * wv.w;
            }
            ushort4 o;
            o.x = f2bf(a.x); o.y = f2bf(a.y); o.z = f2bf(a.z); o.w = f2bf(a.w);
            *(ushort4*)&h_c[(size_t)(s_off[g] + ii) * 128 + j4] = o;
        }
    }
}

// ---------------- gemm1: pair(gathered from h_c) @ lw1t^T -> relu+lb1 -> hid ----------
// R8 config: BK=64, 33.8KB LDS, (256,4) — measured local optimum.
__global__ __launch_bounds__(256, 4) void gemm1_kernel(
    const unsigned short* __restrict__ h_c,   // [M_cp][128]
    const short* __restrict__ lw1t,           // [512][256]
    const float* __restrict__ lb1,
    const int* __restrict__ rm_next,
    const int* __restrict__ header,
    unsigned short* __restrict__ hid,         // [crows][512] chunk-local
    int row0, int pm)
{
    __shared__ __align__(16) char smem[33280];   // K-loop: A(16K)+B(16K); epilogue: f32[64][130]
    __shared__ int s_next[128];

    const int Mcp = header[1];
    int rem = Mcp - row0;
    int apm = (rem <= 0) ? 0 : min(pm, (rem + 127) >> 7);
    int pr, pc;
    if (!tile_assign(blockIdx.x, apm, 2, pr, pc)) return;
    const int Rl = pr * 128;                          // chunk-local
    const int R = row0 + Rl;                          // global compact row base

    const int t = threadIdx.x;
    const int w = t >> 6, l = t & 63, q = l >> 4, ln = l & 15;
    const int wr = w >> 1, wc = w & 1;
    char* ldsA = smem;
    char* ldsB = smem + 16384;

    if (t < 128) s_next[t] = rm_next[R + t];
    __syncthreads();

    f32x4 acc[4][4];
    #pragma unroll
    for (int m = 0; m < 4; ++m)
        #pragma unroll
        for (int n = 0; n < 4; ++n) acc[m][n] = 0;

    #pragma unroll
    for (int kt = 0; kt < 4; ++kt) {
        const int k0 = kt * 64;
        // ---- stage A: gather pair rows (pre-swizzled source)
        #pragma unroll
        for (int i = 0; i < 4; ++i) {
            int o = i * 4096 + t * 16;
            int row = o >> 7, colb = o & 127;
            int colb2 = colb ^ ((row & 7) << 4);
            int k = k0 + (colb2 >> 1);                // 0..255 (compile-time half per kt)
            int srow, kk2;
            if (k < 128) { srow = R + row; kk2 = k; }
            else { srow = s_next[row]; kk2 = k - 128; }
            gload16(h_c + (size_t)srow * 128 + kk2, ldsA + o);
        }
        // ---- stage B from lw1t
        #pragma unroll
        for (int i = 0; i < 4; ++i) {
            int o = i * 4096 + t * 16;
            int row = o >> 7, colb = o & 127;
            int colb2 = colb ^ ((row & 7) << 4);
            gload16(lw1t + (size_t)(pc * 128 + row) * 256 + k0 + (colb2 >> 1), ldsB + o);
        }
        asm volatile("s_waitcnt vmcnt(0)");
        __syncthreads();
        #pragma unroll
        for (int kk = 0; kk < 2; ++kk) {
            bf16x8 af[4], bf[4];
            #pragma unroll
            for (int m = 0; m < 4; ++m) {
                int row = wr * 64 + m * 16 + ln;
                int off = (row * 128 + kk * 64 + q * 16) ^ ((row & 7) << 4);
                af[m] = *(const bf16x8*)(ldsA + off);
            }
            #pragma unroll
            for (int n = 0; n < 4; ++n) {
                int row = wc * 64 + n * 16 + ln;
                int off = (row * 128 + kk * 64 + q * 16) ^ ((row & 7) << 4);
                bf[n] = *(const bf16x8*)(ldsB + off);
            }
            #pragma unroll
            for (int m = 0; m < 4; ++m)
                #pragma unroll
                for (int n = 0; n < 4; ++n)
                    acc[m][n] = MFMA16(af[m], bf[n], acc[m][n]);
        }
        __syncthreads();
    }

    // ---- epilogue: relu+bias -> stage 64-row halves to LDS f32 -> vectorized bf16 write.
    float* s_f32 = (float*)smem;        // [64][130]
    const int erow = t >> 2;            // 0..63
    const int ecl = (t & 3) * 8;        // col base; +j*32 per store
    #pragma unroll 1
    for (int h = 0; h < 2; ++h) {
        if (wr == h) {
            #pragma unroll
            for (int n = 0; n < 4; ++n) {
                int col = wc * 64 + n * 16 + ln;          // tile-local
                float bias = lb1[pc * 128 + col];
                #pragma unroll
                for (int m = 0; m < 4; ++m)
                    #pragma unroll
                    for (int r = 0; r < 4; ++r)
                        s_f32[(m * 16 + q * 4 + r) * 130 + col] =
                            fmaxf(acc[m][n][r] + bias, 0.f);
            }
        }
        __syncthreads();
        {
            const size_t gr = (size_t)(Rl + h * 64 + erow) * 512 + pc * 128;
            #pragma unroll
            for (int j = 0; j < 4; ++j) {
                int c0 = ecl + j * 32;
                float4 a = *(const float4*)&s_f32[erow * 130 + c0];
                float4 b = *(const float4*)&s_f32[erow * 130 + c0 + 4];
                u16x8 o;
                o[0] = f2bf(a.x); o[1] = f2bf(a.y); o[2] = f2bf(a.z); o[3] = f2bf(a.w);
                o[4] = f2bf(b.x); o[5] = f2bf(b.y); o[6] = f2bf(b.z); o[7] = f2bf(b.w);
                *(u16x8*)&hid[gr + c0] = o;
            }
        }
        __syncthreads();
    }
}

// ---------------- gemm2: hid @ lw2t^T + segmented maxpool -> scratch partials ----------
// R8 config: BK=64, 33.8KB LDS, (256,4).
__global__ __launch_bounds__(256, 4) void gemm2_kernel(
    const unsigned short* __restrict__ hid,   // [crows][512] chunk-local
    const short* __restrict__ lw2t,           // [1024][512]
    const int* __restrict__ rm_b,
    const int* __restrict__ scanv,
    const int* __restrict__ header,
    float* __restrict__ scratch,              // [4096][2][1024] f32
    int row0, int pm)
{
    __shared__ __align__(16) char smem[33280];   // K-loop: A(16K)+B(16K); epilogue: f32[64][130]
    __shared__ int s_batch[128];

    const int Mcp = header[1];
    int rem = Mcp - row0;
    int apm = (rem <= 0) ? 0 : min(pm, (rem + 127) >> 7);
    int pr, pc;
    if (!tile_assign(blockIdx.x, apm, 3, pr, pc)) return;
    const int Rl = pr * 128;
    const int R = row0 + Rl;

    const int t = threadIdx.x;
    const int w = t >> 6, l = t & 63, q = l >> 4, ln = l & 15;
    const int wr = w >> 1, wc = w & 1;
    char* ldsA = smem;
    char* ldsB = smem + 16384;

    if (t < 128) s_batch[t] = rm_b[R + t];
    __syncthreads();

    f32x4 acc[4][4];
    #pragma unroll
    for (int m = 0; m < 4; ++m)
        #pragma unroll
        for (int n = 0; n < 4; ++n) acc[m][n] = 0;

    for (int kt = 0; kt < 8; ++kt) {
        const int k0 = kt * 64;
        #pragma unroll
        for (int i = 0; i < 4; ++i) {
            int o = i * 4096 + t * 16;
            int row = o >> 7, colb = o & 127;
            int colb2 = colb ^ ((row & 7) << 4);
            gload16(hid + (size_t)(Rl + row) * 512 + k0 + (colb2 >> 1), ldsA + o);
        }
        #pragma unroll
        for (int i = 0; i < 4; ++i) {
            int o = i * 4096 + t * 16;
            int row = o >> 7, colb = o & 127;
            int colb2 = colb ^ ((row & 7) << 4);
            gload16(lw2t + (size_t)(pc * 128 + row) * 512 + k0 + (colb2 >> 1), ldsB + o);
        }
        asm volatile("s_waitcnt vmcnt(0)");
        __syncthreads();
        #pragma unroll
        for (int kk = 0; kk < 2; ++kk) {
            bf16x8 af[4], bf[4];
            #pragma unroll
            for (int m = 0; m < 4; ++m) {
                int row = wr * 64 + m * 16 + ln;
                int off = (row * 128 + kk * 64 + q * 16) ^ ((row & 7) << 4);
                af[m] = *(const bf16x8*)(ldsA + off);
            }
            #pragma unroll
            for (int n = 0; n < 4; ++n) {
                int row = wc * 64 + n * 16 + ln;
                int off = (row * 128 + kk * 64 + q * 16) ^ ((row & 7) << 4);
                bf[n] = *(const bf16x8*)(ldsB + off);
            }
            #pragma unroll
            for (int m = 0; m < 4; ++m)
                #pragma unroll
                for (int n = 0; n < 4; ++n)
                    acc[m][n] = MFMA16(af[m], bf[n], acc[m][n]);
        }
        __syncthreads();
    }

    // ---- segmented maxpool epilogue: stage 64-row halves, walk 32-row units.
    // A batch (n<=25<32) spans at most 2 consecutive 32-row units ->
    // slot = (batch started before this unit) ? 1 : 0.
    // s_f32 holds only the current 64-row HALF: index half-local (esub*32+row).
    float* s_f32 = (float*)smem;    // [64][130] f32
    const int ecol = t & 127, esub = t >> 7;     // 256 threads: 128 cols x 2 units
    #pragma unroll 1
    for (int h = 0; h < 2; ++h) {
        if (wr == h) {
            #pragma unroll
            for (int m = 0; m < 4; ++m)
                #pragma unroll
                for (int n = 0; n < 4; ++n)
                    #pragma unroll
                    for (int r = 0; r < 4; ++r)
                        s_f32[(m * 16 + q * 4 + r) * 130 + wc * 64 + n * 16 + ln] = acc[m][n][r];
        }
        __syncthreads();
        {
            const int ub = R + h * 64 + esub * 32;   // unit base (global row)
            const int rb = h * 64 + esub * 32;       // tile-local base (s_batch index)
            const int lb = esub * 32;                // half-local base (s_f32 index)
            int curb = s_batch[rb];
            float curmax = s_f32[lb * 130 + ecol];
            #pragma unroll 8
            for (int row = 1; row < 32; ++row) {
                int b = s_batch[rb + row];
                float v = s_f32[(lb + row) * 130 + ecol];
                if (b == curb) {
                    curmax = fmaxf(curmax, v);
                } else {
                    if (curb >= 0) {
                        int slot = (scanv[curb] < ub) ? 1 : 0;
                        scratch[((size_t)curb * 2 + slot) * 1024 + pc * 128 + ecol] = curmax;
                    }
                    curb = b;
                    curmax = v;
                }
            }
            if (curb >= 0) {
                int slot = (scanv[curb] < ub) ? 1 : 0;
                scratch[((size_t)curb * 2 + slot) * 1024 + pc * 128 + ecol] = curmax;
            }
        }
        __syncthreads();
    }
}

// ---------------- merge: max of <=2 partials + lb2 -> pooled bf16 ----------------
__global__ void merge_kernel(const float* __restrict__ scratch, const int* __restrict__ scanv,
                             const float* __restrict__ lb2, unsigned short* __restrict__ pooled_b)
{
    const int b = blockIdx.x;                 // 4096 blocks; thread t does cols 4t..4t+3
    const int col4 = threadIdx.x * 4;
    const int o0 = scanv[b], o1 = scanv[b + 1];
    const bool spans = (o0 >> 5) != ((o1 - 1) >> 5);    // 32-row units
    float4 v = *(const float4*)&scratch[((size_t)b * 2) * 1024 + col4];
    if (spans) {
        float4 u = *(const float4*)&scratch[((size_t)b * 2 + 1) * 1024 + col4];
        v.x = fmaxf(v.x, u.x); v.y = fmaxf(v.y, u.y);
        v.z = fmaxf(v.z, u.z); v.w = fmaxf(v.w, u.w);
    }
    float4 bb = *(const float4*)(lb2 + col4);
    ushort4 o;
    o.x = f2bf(v.x + bb.x); o.y = f2bf(v.y + bb.y);
    o.z = f2bf(v.z + bb.z); o.w = f2bf(v.w + bb.w);
    *(ushort4*)&pooled_b[(size_t)b * 1024 + col4] = o;
}

// ---------------- final: pooled[4096,1024] @ fw[1024,511] + fb ----------------
// BN=128 per block (grid y=4): halves redundant pooled re-reads vs BN=64.
__global__ __launch_bounds__(512, 2) void final_kernel(
    const unsigned short* __restrict__ pooled_b,
    const short* __restrict__ fwt,    // bf16 [512][1024]
    const float* __restrict__ fb,
    float* __restrict__ out)
{
    const int tid = threadIdx.x;
    const int w = tid >> 6, l = tid & 63, q = l >> 4, ln = l & 15;
    const int rb = blockIdx.x * 128 + w * 16;
    const int nb0 = blockIdx.y * 128;

    f32x4 acc[8];
    #pragma unroll
    for (int j = 0; j < 8; ++j) acc[j] = 0;

    const short* pb = (const short*)pooled_b;
    #pragma unroll 2
    for (int ks = 0; ks < 32; ++ks) {
        bf16x8 a = *(const bf16x8*)(pb + (rb + ln) * 1024 + ks * 32 + q * 8);
        #pragma unroll
        for (int j = 0; j < 8; ++j) {
            bf16x8 bf = *(const bf16x8*)(fwt + (nb0 + j * 16 + ln) * 1024 + ks * 32 + q * 8);
            acc[j] = MFMA16(a, bf, acc[j]);
        }
    }
    #pragma unroll
    for (int j = 0; j < 8; ++j) {
        int col = nb0 + j * 16 + ln;
        if (col < 511) {
            float bias = fb[col];
            #pragma unroll
            for (int r = 0; r < 4; ++r) {
                int row = rb + q * 4 + r;
                out[row * 511 + col] = acc[j][r] + bias;
            }
        }
    }
}

extern "C" void kernel_launch(void* const* d_in, const int* in_sizes, int n_in,
                              void* d_out, int out_size, void* d_ws, size_t ws_size,
                              hipStream_t stream)
{
    const float* fpoc = (const float*)d_in[0];
    const float* cw1  = (const float*)d_in[1];
    const float* cb1  = (const float*)d_in[2];
    const float* cw2  = (const float*)d_in[3];
    const float* cb2  = (const float*)d_in[4];
    const float* lw1  = (const float*)d_in[5];
    const float* lb1  = (const float*)d_in[6];
    const float* lw2  = (const float*)d_in[7];
    const float* lb2  = (const float*)d_in[8];
    const float* fw   = (const float*)d_in[9];
    const float* fb   = (const float*)d_in[10];
    const int*  nfpc  = (const int*)d_in[11];

    char* ws = (char*)d_ws;
    unsigned short* pooled_b = (unsigned short*)(ws + WS_POOLED);
    short* lw1t   = (short*)(ws + WS_LW1T);
    short* lw2t   = (short*)(ws + WS_LW2T);
    short* fwt    = (short*)(ws + WS_FWT);
    int*   scanv  = (int*)(ws + WS_SCAN);
    int*   header = (int*)(ws + WS_HEADER);
    int*   rm_b   = (int*)(ws + WS_RMB);
    int*   rm_next= (int*)(ws + WS_RMNEXT);
    unsigned short* h_c = (unsigned short*)(ws + WS_HC);
    float* scratch = (float*)(ws + WS_SCRATCH);
    unsigned short* hid = (unsigned short*)(ws + WS_HID);

    // adaptive chunking of hid (worst case 102400 rows x 512 x bf16 = 100 MB)
    size_t avail = (ws_size > WS_HID) ? ws_size - WS_HID : 0;
    int n_chunks = 1;
    while (n_chunks < 16 && (size_t)(104857600u / n_chunks) > avail) n_chunks <<= 1;
    const int crows = 102400 / n_chunks;
    const int pm = crows / 128;

    hipLaunchKernelGGL(prep_kernel, dim3(689), dim3(256), 0, stream,
                       lw1, lw2, fw, lw1t, lw2t, fwt, nfpc, scanv, header,
                       rm_b, rm_next, h_c);
    hipLaunchKernelGGL(corner_kernel, dim3(1024), dim3(256), 0, stream,
                       fpoc, cw1, cb1, cw2, cb2, scanv, h_c);
    const int g1 = ((pm * 4 + 7) / 8) * 8;   // grid covers worst-case per-XCD share
    const int g2 = pm * 8;
    for (int c = 0; c < n_chunks; ++c) {
        int row0 = c * crows;
        hipLaunchKernelGGL(gemm1_kernel, dim3(g1), dim3(256), 0, stream,
                           h_c, lw1t, lb1, rm_next, header, hid, row0, pm);
        hipLaunchKernelGGL(gemm2_kernel, dim3(g2), dim3(256), 0, stream,
                           hid, lw2t, rm_b, scanv, header, scratch, row0, pm);
    }
    hipLaunchKernelGGL(merge_kernel, dim3(4096), dim3(256), 0, stream,
                       scratch, scanv, lb2, pooled_b);
    hipLaunchKernelGGL(final_kernel, dim3(32, 4), dim3(512), 0, stream,
                       pooled_b, fwt, fb, (float*)d_out);
}

// Round 14
// 211.959 us; speedup vs baseline: 1.2428x; 1.0908x over previous
//
#include <hip/hip_runtime.h>

typedef __attribute__((ext_vector_type(8))) short bf16x8;
typedef __attribute__((ext_vector_type(4))) float f32x4;
typedef __attribute__((ext_vector_type(8))) unsigned short u16x8;

#define MFMA16(a, b, c) __builtin_amdgcn_mfma_f32_16x16x32_bf16((a), (b), (c), 0, 0, 0)

static __device__ __forceinline__ unsigned short f2bf(float x) {
    union { float f; unsigned u; } v; v.f = x;
    unsigned r = v.u + 0x7fffu + ((v.u >> 16) & 1u);
    return (unsigned short)(r >> 16);
}

// async global->LDS, 16B per lane. LDS dest = wave base + lane*16 (linear).
static __device__ __forceinline__ void gload16(const void* g, void* l) {
    __builtin_amdgcn_global_load_lds(
        (const __attribute__((address_space(1))) unsigned int*)g,
        (__attribute__((address_space(3))) unsigned int*)l, 16, 0, 0);
}

// Balanced data-dependent tile assignment: XCD k = bid&7 gets active-tile range
// [T*k/8, T*(k+1)/8) (bijective chunked, m204). pc-fast => contiguous pr per XCD.
static __device__ __forceinline__ bool tile_assign(int bid, int apm, int npc_log2,
                                                   int& pr, int& pc) {
    const int k = bid & 7, j = bid >> 3;
    const int T = apm << npc_log2;
    const int lo = (T * k) >> 3, hi = (T * (k + 1)) >> 3;
    const int tix = lo + j;
    if (tix >= hi) return false;
    pc = tix & ((1 << npc_log2) - 1);
    pr = tix >> npc_log2;
    return true;
}

// ---------------- workspace layout (bytes) ----------------
#define WS_POOLED   0u          //  8,388,608  bf16 [4096][1024]
#define WS_LW1T     8388608u    //    262,144  bf16 [512][256]
#define WS_LW2T     8650752u    //  1,048,576  bf16 [1024][512]
#define WS_FWT      9699328u    //  1,048,576  bf16 [512][1024]
#define WS_SCAN     10747904u   //     16,640  int [4097]
#define WS_HEADER   10764544u   //        256  int: {M_c, M_cp}
#define WS_RMB      10764800u   //    409,600  int [102400]
#define WS_RMNEXT   11174400u   //    409,600  int [102400]
#define WS_HC       11584000u   // 26,214,400  bf16 [102400][128]
#define WS_SCRATCH  37798400u   // 33,554,432  f32 [4096][2][1024]
#define WS_HID      71352832u   // up to 104,857,600  bf16 [102400][512]

// ---------------- convert (LDS-tiled transpose fp32->bf16) + scan (block 288) ------
// 288 tile-blocks of 64x64; coalesced loads, lds[64][65] (conflict-free column
// reads), coalesced ushort4 stores.
__global__ void convert_scan_kernel(
    const float* __restrict__ lw1, const float* __restrict__ lw2, const float* __restrict__ fw,
    short* __restrict__ lw1t, short* __restrict__ lw2t, short* __restrict__ fwt,
    const int* __restrict__ nfpc, int* __restrict__ scanv, int* __restrict__ header)
{
    const int bid = blockIdx.x;
    const int t = threadIdx.x;
    if (bid == 288) {
        // exclusive prefix sum of nfpc[4096]
        __shared__ int s[256];
        int loc[16]; int sum = 0;
        #pragma unroll
        for (int i = 0; i < 16; ++i) { loc[i] = sum; sum += nfpc[t * 16 + i]; }
        s[t] = sum;
        __syncthreads();
        for (int d = 1; d < 256; d <<= 1) {
            int v = (t >= d) ? s[t - d] : 0;
            __syncthreads();
            s[t] += v;
            __syncthreads();
        }
        int excl = (t == 0) ? 0 : s[t - 1];
        #pragma unroll
        for (int i = 0; i < 16; ++i) scanv[t * 16 + i] = excl + loc[i];
        if (t == 255) {
            int M = s[255];
            scanv[4096] = M;
            header[0] = M;
            header[1] = (M + 127) & ~127;
        }
        return;
    }

    // decode (matrix, tile): dst[n][k] = src[k][n]
    const float* src; short* dst;
    int srcN, nmax, dstK, n0, k0;
    if (bid < 32) {            // lw1t [512][256] <- lw1 [256][512]; 8 x 4 tiles
        int tn = bid >> 2, tk = bid & 3;
        src = lw1; srcN = 512; nmax = 512; dst = lw1t; dstK = 256;
        n0 = tn * 64; k0 = tk * 64;
    } else if (bid < 160) {    // lw2t [1024][512] <- lw2 [512][1024]; 16 x 8 tiles
        int u = bid - 32; int tn = u >> 3, tk = u & 7;
        src = lw2; srcN = 1024; nmax = 1024; dst = lw2t; dstK = 512;
        n0 = tn * 64; k0 = tk * 64;
    } else {                   // fwt [512][1024] <- fw [1024][511] (row 511 = 0); 8 x 16 tiles
        int u = bid - 160; int tn = u >> 4, tk = u & 15;
        src = fw; srcN = 511; nmax = 511; dst = fwt; dstK = 1024;
        n0 = tn * 64; k0 = tk * 64;
    }

    __shared__ float lds[64 * 65];
    for (int e = t; e < 4096; e += 256) {       // load: rows=k, cols=n (coalesced over n)
        int r = e >> 6, c = e & 63;
        int n = n0 + c;
        lds[r * 65 + c] = (n < nmax) ? src[(size_t)(k0 + r) * srcN + n] : 0.0f;
    }
    __syncthreads();
    for (int e = t; e < 1024; e += 256) {       // store: rows=n, cols=k (coalesced ushort4)
        int rn = e >> 4, c4 = (e & 15) * 4;
        ushort4 o;
        o.x = f2bf(lds[(c4 + 0) * 65 + rn]);
        o.y = f2bf(lds[(c4 + 1) * 65 + rn]);
        o.z = f2bf(lds[(c4 + 2) * 65 + rn]);
        o.w = f2bf(lds[(c4 + 3) * 65 + rn]);
        *(ushort4*)&dst[(size_t)(n0 + rn) * dstK + k0 + c4] = o;
    }
}

// ---------------- rowmap + zero h_c padding rows ----------------
__global__ void rowmap_kernel(const int* __restrict__ scanv, const int* __restrict__ header,
                              int* __restrict__ rm_b, int* __restrict__ rm_next,
                              unsigned short* __restrict__ h_c)
{
    int r = blockIdx.x * 256 + threadIdx.x;     // grid covers 102400
    if (r >= 102400) return;
    const int Mc = header[0];
    if (r >= Mc) {
        rm_b[r] = -1; rm_next[r] = r;
        if (r < header[1]) {
            ushort4 z = {0, 0, 0, 0};
            #pragma unroll
            for (int j = 0; j < 128; j += 4)
                *(ushort4*)&h_c[(size_t)r * 128 + j] = z;
        }
        return;
    }
    int lo = 0, hi = 4096;
    while (hi - lo > 1) { int mid = (lo + hi) >> 1; if (scanv[mid] <= r) lo = mid; else hi = mid; }
    int b = lo, ii = r - scanv[b], n = scanv[b + 1] - scanv[b];
    rm_b[r] = b;
    rm_next[r] = (ii + 1 == n) ? scanv[b] : r + 1;
}

// ---------------- corner MLP -> compacted h_c bf16 [M_c][128] ----------------
#define CB 4
__global__ __launch_bounds__(256, 2) void corner_kernel(
    const float* __restrict__ fpoc,
    const float* __restrict__ cw1, const float* __restrict__ cb1,
    const float* __restrict__ cw2, const float* __restrict__ cb2,
    const int* __restrict__ scanv,
    unsigned short* __restrict__ h_c)
{
    __shared__ float s_h1[CB * 25 * 64];
    __shared__ float s_cw2[64 * 128];
    __shared__ float s_x[CB * 25 * 2];
    __shared__ int s_off[CB], s_nn[CB];
    const int b0 = blockIdx.x * CB;
    const int t = threadIdx.x;

    for (int e = t; e < 64 * 128; e += 256) s_cw2[e] = cw2[e];
    for (int e = t; e < CB * 50; e += 256) s_x[e] = fpoc[b0 * 50 + e];
    if (t < CB) { int o = scanv[b0 + t]; s_off[t] = o; s_nn[t] = scanv[b0 + t + 1] - o; }
    __syncthreads();

    for (int e = t; e < CB * 25 * 64; e += 256) {
        int i = e >> 6, j = e & 63;
        float v = s_x[i * 2] * cw1[j] + s_x[i * 2 + 1] * cw1[64 + j] + cb1[j];
        s_h1[e] = fmaxf(v, 0.f);
    }
    __syncthreads();

    // layer 2: float4 per thread (ds_read_b128 on cw2)
    for (int e = t; e < CB * 25 * 32; e += 256) {
        int i = e >> 5, j4 = (e & 31) * 4;
        int g = i / 25, ii = i % 25;
        if (ii < s_nn[g]) {
            float4 a = *(const float4*)(cb2 + j4);
            const float* h1r = &s_h1[i * 64];
            #pragma unroll
            for (int k = 0; k < 64; ++k) {
                float hv = h1r[k];
                float4 wv = *(const float4*)(s_cw2 + k * 128 + j4);
                a.x += hv * wv.x; a.y += hv * wv.y; a.z += hv * wv.z; a.w += hv * wv.w;
            }
            ushort4 o;
            o.x = f2bf(a.x); o.y = f2bf(a.y); o.z = f2bf(a.z); o.w = f2bf(a.w);
            *(ushort4*)&h_c[(size_t)(s_off[g] + ii) * 128 + j4] = o;
        }
    }
}

// ---------------- gemm1: pair(gathered from h_c) @ lw1t^T -> relu+lb1 -> hid ----------
// R8 config: BK=64, 33.8KB LDS, (256,4) — measured local optimum.
__global__ __launch_bounds__(256, 4) void gemm1_kernel(
    const unsigned short* __restrict__ h_c,   // [M_cp][128]
    const short* __restrict__ lw1t,           // [512][256]
    const float* __restrict__ lb1,
    const int* __restrict__ rm_next,
    const int* __restrict__ header,
    unsigned short* __restrict__ hid,         // [crows][512] chunk-local
    int row0, int pm)
{
    __shared__ __align__(16) char smem[33280];   // K-loop: A(16K)+B(16K); epilogue: f32[64][130]
    __shared__ int s_next[128];

    const int Mcp = header[1];
    int rem = Mcp - row0;
    int apm = (rem <= 0) ? 0 : min(pm, (rem + 127) >> 7);
    int pr, pc;
    if (!tile_assign(blockIdx.x, apm, 2, pr, pc)) return;
    const int Rl = pr * 128;                          // chunk-local
    const int R = row0 + Rl;                          // global compact row base

    const int t = threadIdx.x;
    const int w = t >> 6, l = t & 63, q = l >> 4, ln = l & 15;
    const int wr = w >> 1, wc = w & 1;
    char* ldsA = smem;
    char* ldsB = smem + 16384;

    if (t < 128) s_next[t] = rm_next[R + t];
    __syncthreads();

    f32x4 acc[4][4];
    #pragma unroll
    for (int m = 0; m < 4; ++m)
        #pragma unroll
        for (int n = 0; n < 4; ++n) acc[m][n] = 0;

    #pragma unroll
    for (int kt = 0; kt < 4; ++kt) {
        const int k0 = kt * 64;
        // ---- stage A: gather pair rows (pre-swizzled source)
        #pragma unroll
        for (int i = 0; i < 4; ++i) {
            int o = i * 4096 + t * 16;
            int row = o >> 7, colb = o & 127;
            int colb2 = colb ^ ((row & 7) << 4);
            int k = k0 + (colb2 >> 1);                // 0..255 (compile-time half per kt)
            int srow, kk2;
            if (k < 128) { srow = R + row; kk2 = k; }
            else { srow = s_next[row]; kk2 = k - 128; }
            gload16(h_c + (size_t)srow * 128 + kk2, ldsA + o);
        }
        // ---- stage B from lw1t
        #pragma unroll
        for (int i = 0; i < 4; ++i) {
            int o = i * 4096 + t * 16;
            int row = o >> 7, colb = o & 127;
            int colb2 = colb ^ ((row & 7) << 4);
            gload16(lw1t + (size_t)(pc * 128 + row) * 256 + k0 + (colb2 >> 1), ldsB + o);
        }
        asm volatile("s_waitcnt vmcnt(0)");
        __syncthreads();
        #pragma unroll
        for (int kk = 0; kk < 2; ++kk) {
            bf16x8 af[4], bf[4];
            #pragma unroll
            for (int m = 0; m < 4; ++m) {
                int row = wr * 64 + m * 16 + ln;
                int off = (row * 128 + kk * 64 + q * 16) ^ ((row & 7) << 4);
                af[m] = *(const bf16x8*)(ldsA + off);
            }
            #pragma unroll
            for (int n = 0; n < 4; ++n) {
                int row = wc * 64 + n * 16 + ln;
                int off = (row * 128 + kk * 64 + q * 16) ^ ((row & 7) << 4);
                bf[n] = *(const bf16x8*)(ldsB + off);
            }
            #pragma unroll
            for (int m = 0; m < 4; ++m)
                #pragma unroll
                for (int n = 0; n < 4; ++n)
                    acc[m][n] = MFMA16(af[m], bf[n], acc[m][n]);
        }
        __syncthreads();
    }

    // ---- epilogue: relu+bias -> stage 64-row halves to LDS f32 -> vectorized bf16 write.
    float* s_f32 = (float*)smem;        // [64][130]
    const int erow = t >> 2;            // 0..63
    const int ecl = (t & 3) * 8;        // col base; +j*32 per store
    #pragma unroll 1
    for (int h = 0; h < 2; ++h) {
        if (wr == h) {
            #pragma unroll
            for (int n = 0; n < 4; ++n) {
                int col = wc * 64 + n * 16 + ln;          // tile-local
                float bias = lb1[pc * 128 + col];
                #pragma unroll
                for (int m = 0; m < 4; ++m)
                    #pragma unroll
                    for (int r = 0; r < 4; ++r)
                        s_f32[(m * 16 + q * 4 + r) * 130 + col] =
                            fmaxf(acc[m][n][r] + bias, 0.f);
            }
        }
        __syncthreads();
        {
            const size_t gr = (size_t)(Rl + h * 64 + erow) * 512 + pc * 128;
            #pragma unroll
            for (int j = 0; j < 4; ++j) {
                int c0 = ecl + j * 32;
                float4 a = *(const float4*)&s_f32[erow * 130 + c0];
                float4 b = *(const float4*)&s_f32[erow * 130 + c0 + 4];
                u16x8 o;
                o[0] = f2bf(a.x); o[1] = f2bf(a.y); o[2] = f2bf(a.z); o[3] = f2bf(a.w);
                o[4] = f2bf(b.x); o[5] = f2bf(b.y); o[6] = f2bf(b.z); o[7] = f2bf(b.w);
                *(u16x8*)&hid[gr + c0] = o;
            }
        }
        __syncthreads();
    }
}

// ---------------- gemm2: hid @ lw2t^T + segmented maxpool -> scratch partials ----------
// R8 config: BK=64, 33.8KB LDS, (256,4).
__global__ __launch_bounds__(256, 4) void gemm2_kernel(
    const unsigned short* __restrict__ hid,   // [crows][512] chunk-local
    const short* __restrict__ lw2t,           // [1024][512]
    const int* __restrict__ rm_b,
    const int* __restrict__ scanv,
    const int* __restrict__ header,
    float* __restrict__ scratch,              // [4096][2][1024] f32
    int row0, int pm)
{
    __shared__ __align__(16) char smem[33280];   // K-loop: A(16K)+B(16K); epilogue: f32[64][130]
    __shared__ int s_batch[128];

    const int Mcp = header[1];
    int rem = Mcp - row0;
    int apm = (rem <= 0) ? 0 : min(pm, (rem + 127) >> 7);
    int pr, pc;
    if (!tile_assign(blockIdx.x, apm, 3, pr, pc)) return;
    const int Rl = pr * 128;
    const int R = row0 + Rl;

    const int t = threadIdx.x;
    const int w = t >> 6, l = t & 63, q = l >> 4, ln = l & 15;
    const int wr = w >> 1, wc = w & 1;
    char* ldsA = smem;
    char* ldsB = smem + 16384;

    if (t < 128) s_batch[t] = rm_b[R + t];
    __syncthreads();

    f32x4 acc[4][4];
    #pragma unroll
    for (int m = 0; m < 4; ++m)
        #pragma unroll
        for (int n = 0; n < 4; ++n) acc[m][n] = 0;

    for (int kt = 0; kt < 8; ++kt) {
        const int k0 = kt * 64;
        #pragma unroll
        for (int i = 0; i < 4; ++i) {
            int o = i * 4096 + t * 16;
            int row = o >> 7, colb = o & 127;
            int colb2 = colb ^ ((row & 7) << 4);
            gload16(hid + (size_t)(Rl + row) * 512 + k0 + (colb2 >> 1), ldsA + o);
        }
        #pragma unroll
        for (int i = 0; i < 4; ++i) {
            int o = i * 4096 + t * 16;
            int row = o >> 7, colb = o & 127;
            int colb2 = colb ^ ((row & 7) << 4);
            gload16(lw2t + (size_t)(pc * 128 + row) * 512 + k0 + (colb2 >> 1), ldsB + o);
        }
        asm volatile("s_waitcnt vmcnt(0)");
        __syncthreads();
        #pragma unroll
        for (int kk = 0; kk < 2; ++kk) {
            bf16x8 af[4], bf[4];
            #pragma unroll
            for (int m = 0; m < 4; ++m) {
                int row = wr * 64 + m * 16 + ln;
                int off = (row * 128 + kk * 64 + q * 16) ^ ((row & 7) << 4);
                af[m] = *(const bf16x8*)(ldsA + off);
            }
            #pragma unroll
            for (int n = 0; n < 4; ++n) {
                int row = wc * 64 + n * 16 + ln;
                int off = (row * 128 + kk * 64 + q * 16) ^ ((row & 7) << 4);
                bf[n] = *(const bf16x8*)(ldsB + off);
            }
            #pragma unroll
            for (int m = 0; m < 4; ++m)
                #pragma unroll
                for (int n = 0; n < 4; ++n)
                    acc[m][n] = MFMA16(af[m], bf[n], acc[m][n]);
        }
        __syncthreads();
    }

    // ---- segmented maxpool epilogue: stage 64-row halves, walk 32-row units.
    // A batch (n<=25<32) spans at most 2 consecutive 32-row units ->
    // slot = (batch started before this unit) ? 1 : 0.
    // s_f32 holds only the current 64-row HALF: index half-local (esub*32+row).
    float* s_f32 = (float*)smem;    // [64][130] f32
    const int ecol = t & 127, esub = t >> 7;     // 256 threads: 128 cols x 2 units
    #pragma unroll 1
    for (int h = 0; h < 2; ++h) {
        if (wr == h) {
            #pragma unroll
            for (int m = 0; m < 4; ++m)
                #pragma unroll
                for (int n = 0; n < 4; ++n)
                    #pragma unroll
                    for (int r = 0; r < 4; ++r)
                        s_f32[(m * 16 + q * 4 + r) * 130 + wc * 64 + n * 16 + ln] = acc[m][n][r];
        }
        __syncthreads();
        {
            const int ub = R + h * 64 + esub * 32;   // unit base (global row)
            const int rb = h * 64 + esub * 32;       // tile-local base (s_batch index)
            const int lb = esub * 32;                // half-local base (s_f32 index)
            int curb = s_batch[rb];
            float curmax = s_f32[lb * 130 + ecol];
            #pragma unroll 8
            for (int row = 1; row < 32; ++row) {
                int b = s_batch[rb + row];
                float v = s_f32[(lb + row) * 130 + ecol];
                if (b == curb) {
                    curmax = fmaxf(curmax, v);
                } else {
                    if (curb >= 0) {
                        int slot = (scanv[curb] < ub) ? 1 : 0;
                        scratch[((size_t)curb * 2 + slot) * 1024 + pc * 128 + ecol] = curmax;
                    }
                    curb = b;
                    curmax = v;
                }
            }
            if (curb >= 0) {
                int slot = (scanv[curb] < ub) ? 1 : 0;
                scratch[((size_t)curb * 2 + slot) * 1024 + pc * 128 + ecol] = curmax;
            }
        }
        __syncthreads();
    }
}

// ---------------- merge: max of <=2 partials + lb2 -> pooled bf16 ----------------
__global__ void merge_kernel(const float* __restrict__ scratch, const int* __restrict__ scanv,
                             const float* __restrict__ lb2, unsigned short* __restrict__ pooled_b)
{
    const int b = blockIdx.x;                 // 4096 blocks; thread t does cols 4t..4t+3
    const int col4 = threadIdx.x * 4;
    const int o0 = scanv[b], o1 = scanv[b + 1];
    const bool spans = (o0 >> 5) != ((o1 - 1) >> 5);    // 32-row units
    float4 v = *(const float4*)&scratch[((size_t)b * 2) * 1024 + col4];
    if (spans) {
        float4 u = *(const float4*)&scratch[((size_t)b * 2 + 1) * 1024 + col4];
        v.x = fmaxf(v.x, u.x); v.y = fmaxf(v.y, u.y);
        v.z = fmaxf(v.z, u.z); v.w = fmaxf(v.w, u.w);
    }
    float4 bb = *(const float4*)(lb2 + col4);
    ushort4 o;
    o.x = f2bf(v.x + bb.x); o.y = f2bf(v.y + bb.y);
    o.z = f2bf(v.z + bb.z); o.w = f2bf(v.w + bb.w);
    *(ushort4*)&pooled_b[(size_t)b * 1024 + col4] = o;
}

// ---------------- final: pooled[4096,1024] @ fw[1024,511] + fb ----------------
__global__ __launch_bounds__(512, 2) void final_kernel(
    const unsigned short* __restrict__ pooled_b,
    const short* __restrict__ fwt,    // bf16 [512][1024]
    const float* __restrict__ fb,
    float* __restrict__ out)
{
    const int tid = threadIdx.x;
    const int w = tid >> 6, l = tid & 63, q = l >> 4, ln = l & 15;
    const int rb = blockIdx.x * 128 + w * 16;
    const int nb0 = blockIdx.y * 64;

    f32x4 acc[4];
    #pragma unroll
    for (int j = 0; j < 4; ++j) acc[j] = 0;

    const short* pb = (const short*)pooled_b;
    #pragma unroll 4
    for (int ks = 0; ks < 32; ++ks) {
        bf16x8 a = *(const bf16x8*)(pb + (rb + ln) * 1024 + ks * 32 + q * 8);
        #pragma unroll
        for (int j = 0; j < 4; ++j) {
            bf16x8 bf = *(const bf16x8*)(fwt + (nb0 + j * 16 + ln) * 1024 + ks * 32 + q * 8);
            acc[j] = MFMA16(a, bf, acc[j]);
        }
    }
    #pragma unroll
    for (int j = 0; j < 4; ++j) {
        int col = nb0 + j * 16 + ln;
        if (col < 511) {
            float bias = fb[col];
            #pragma unroll
            for (int r = 0; r < 4; ++r) {
                int row = rb + q * 4 + r;
                out[row * 511 + col] = acc[j][r] + bias;
            }
        }
    }
}

extern "C" void kernel_launch(void* const* d_in, const int* in_sizes, int n_in,
                              void* d_out, int out_size, void* d_ws, size_t ws_size,
                              hipStream_t stream)
{
    const float* fpoc = (const float*)d_in[0];
    const float* cw1  = (const float*)d_in[1];
    const float* cb1  = (const float*)d_in[2];
    const float* cw2  = (const float*)d_in[3];
    const float* cb2  = (const float*)d_in[4];
    const float* lw1  = (const float*)d_in[5];
    const float* lb1  = (const float*)d_in[6];
    const float* lw2  = (const float*)d_in[7];
    const float* lb2  = (const float*)d_in[8];
    const float* fw   = (const float*)d_in[9];
    const float* fb   = (const float*)d_in[10];
    const int*  nfpc  = (const int*)d_in[11];

    char* ws = (char*)d_ws;
    unsigned short* pooled_b = (unsigned short*)(ws + WS_POOLED);
    short* lw1t   = (short*)(ws + WS_LW1T);
    short* lw2t   = (short*)(ws + WS_LW2T);
    short* fwt    = (short*)(ws + WS_FWT);
    int*   scanv  = (int*)(ws + WS_SCAN);
    int*   header = (int*)(ws + WS_HEADER);
    int*   rm_b   = (int*)(ws + WS_RMB);
    int*   rm_next= (int*)(ws + WS_RMNEXT);
    unsigned short* h_c = (unsigned short*)(ws + WS_HC);
    float* scratch = (float*)(ws + WS_SCRATCH);
    unsigned short* hid = (unsigned short*)(ws + WS_HID);

    // adaptive chunking of hid (worst case 102400 rows x 512 x bf16 = 100 MB)
    size_t avail = (ws_size > WS_HID) ? ws_size - WS_HID : 0;
    int n_chunks = 1;
    while (n_chunks < 16 && (size_t)(104857600u / n_chunks) > avail) n_chunks <<= 1;
    const int crows = 102400 / n_chunks;
    const int pm = crows / 128;

    hipLaunchKernelGGL(convert_scan_kernel, dim3(289), dim3(256), 0, stream,
                       lw1, lw2, fw, lw1t, lw2t, fwt, nfpc, scanv, header);
    hipLaunchKernelGGL(rowmap_kernel, dim3(400), dim3(256), 0, stream,
                       scanv, header, rm_b, rm_next, h_c);
    hipLaunchKernelGGL(corner_kernel, dim3(1024), dim3(256), 0, stream,
                       fpoc, cw1, cb1, cw2, cb2, scanv, h_c);
    const int g1 = ((pm * 4 + 7) / 8) * 8;   // grid covers worst-case per-XCD share
    const int g2 = pm * 8;
    for (int c = 0; c < n_chunks; ++c) {
        int row0 = c * crows;
        hipLaunchKernelGGL(gemm1_kernel, dim3(g1), dim3(256), 0, stream,
                           h_c, lw1t, lb1, rm_next, header, hid, row0, pm);
        hipLaunchKernelGGL(gemm2_kernel, dim3(g2), dim3(256), 0, stream,
                           hid, lw2t, rm_b, scanv, header, scratch, row0, pm);
    }
    hipLaunchKernelGGL(merge_kernel, dim3(4096), dim3(256), 0, stream,
                       scratch, scanv, lb2, pooled_b);
    hipLaunchKernelGGL(final_kernel, dim3(32, 8), dim3(512), 0, stream,
                       pooled_b, fwt, fb, (float*)d_out);
}

// Round 15
// 205.742 us; speedup vs baseline: 1.2804x; 1.0302x over previous
//
#include <hip/hip_runtime.h>

typedef __attribute__((ext_vector_type(8))) short bf16x8;
typedef __attribute__((ext_vector_type(4))) float f32x4;
typedef __attribute__((ext_vector_type(8))) unsigned short u16x8;

#define MFMA16(a, b, c) __builtin_amdgcn_mfma_f32_16x16x32_bf16((a), (b), (c), 0, 0, 0)

static __device__ __forceinline__ unsigned short f2bf(float x) {
    union { float f; unsigned u; } v; v.f = x;
    unsigned r = v.u + 0x7fffu + ((v.u >> 16) & 1u);
    return (unsigned short)(r >> 16);
}

// async global->LDS, 16B per lane. LDS dest = wave base + lane*16 (linear).
static __device__ __forceinline__ void gload16(const void* g, void* l) {
    __builtin_amdgcn_global_load_lds(
        (const __attribute__((address_space(1))) unsigned int*)g,
        (__attribute__((address_space(3))) unsigned int*)l, 16, 0, 0);
}

// Balanced data-dependent tile assignment: XCD k = bid&7 gets active-tile range
// [T*k/8, T*(k+1)/8) (bijective chunked, m204). pc-fast => contiguous pr per XCD.
static __device__ __forceinline__ bool tile_assign(int bid, int apm, int npc_log2,
                                                   int& pr, int& pc) {
    const int k = bid & 7, j = bid >> 3;
    const int T = apm << npc_log2;
    const int lo = (T * k) >> 3, hi = (T * (k + 1)) >> 3;
    const int tix = lo + j;
    if (tix >= hi) return false;
    pc = tix & ((1 << npc_log2) - 1);
    pr = tix >> npc_log2;
    return true;
}

// ---------------- workspace layout (bytes) ----------------
#define WS_POOLED   0u          //  8,388,608  bf16 [4096][1024]
#define WS_LW1T     8388608u    //    262,144  bf16 [512][256]
#define WS_LW2T     8650752u    //  1,048,576  bf16 [1024][512]
#define WS_FWT      9699328u    //  1,048,576  bf16 [512][1024]
#define WS_SCAN     10747904u   //     16,640  int [4097]
#define WS_HEADER   10764544u   //        256  int: {M_c, M_cp}
#define WS_RMB      10764800u   //    409,600  int [102400]
#define WS_RMNEXT   11174400u   //    409,600  int [102400]
#define WS_HC       11584000u   // 26,214,400  bf16 [102400][128]
#define WS_SCRATCH  37798400u   // 33,554,432  f32 [4096][2][1024]
#define WS_HID      71352832u   // up to 104,857,600  bf16 [102400][512]

#define CB 4

// ================= fused prep: corner | convert | scan | rowmap =================
// All roles independent (self-derived nfpc prefix sums where needed — validated R12).
// bid 0..1023    : corner MLP (cw2 staged in LDS — R12's L1-direct was the regression)
// bid 1024..1311 : weight transpose tiles (fp32 -> bf16 [N][K]), lds[64][65]
// bid 1312       : global scan -> scanv/header (consumed by gemm1/gemm2/merge)
// bid 1313..1712 : rowmap + zeropad (self-derived scan)
__global__ __launch_bounds__(256) void prep_kernel(
    const float* __restrict__ lw1, const float* __restrict__ lw2, const float* __restrict__ fw,
    short* __restrict__ lw1t, short* __restrict__ lw2t, short* __restrict__ fwt,
    const int* __restrict__ nfpc, int* __restrict__ scanv, int* __restrict__ header,
    const float* __restrict__ fpoc,
    const float* __restrict__ cw1, const float* __restrict__ cb1,
    const float* __restrict__ cw2, const float* __restrict__ cb2,
    int* __restrict__ rm_b, int* __restrict__ rm_next,
    unsigned short* __restrict__ h_c)
{
    __shared__ __align__(16) char pmem[60224];
    const int bid = blockIdx.x;
    const int t = threadIdx.x;

    if (bid < 1024) {
        // ---- corner MLP block (cb = bid), self-derived prefix base (R12-validated)
        const int b0 = bid * CB;
        float* s_cw2 = (float*)pmem;               // 64*128*4 = 32768
        float* s_h1  = (float*)(pmem + 32768);     // CB*25*64*4 = 25600
        float* s_x   = (float*)(pmem + 58368);     // CB*50*4 = 800
        int* s_red   = (int*)(pmem + 59168);       // 256*4 = 1024
        int* s_off   = (int*)(pmem + 60192);       // CB*4
        int* s_nn    = (int*)(pmem + 60208);       // CB*4

        // stage cw2 into LDS (157 TB/s path), load x, compute prefix partials
        for (int e = t; e < 64 * 128; e += 256) s_cw2[e] = cw2[e];
        for (int e = t; e < CB * 50; e += 256) s_x[e] = fpoc[b0 * 50 + e];
        {
            int partial = 0;
            const int c0 = t * 16;
            #pragma unroll
            for (int i = 0; i < 16; ++i) {
                int idx = c0 + i;
                partial += (idx < b0) ? nfpc[idx] : 0;
            }
            s_red[t] = partial;
        }
        __syncthreads();
        for (int d = 128; d > 0; d >>= 1) {
            if (t < d) s_red[t] += s_red[t + d];
            __syncthreads();
        }
        if (t == 0) {
            int o = s_red[0];
            #pragma unroll
            for (int g = 0; g < CB; ++g) {
                s_off[g] = o;
                int nn = nfpc[b0 + g];
                s_nn[g] = nn;
                o += nn;
            }
        }
        __syncthreads();

        // layer 1: h1 = relu(x @ cw1 + cb1)
        for (int e = t; e < CB * 25 * 64; e += 256) {
            int i = e >> 6, j = e & 63;
            float v = s_x[i * 2] * cw1[j] + s_x[i * 2 + 1] * cw1[64 + j] + cb1[j];
            s_h1[e] = fmaxf(v, 0.f);
        }
        __syncthreads();

        // layer 2: float4 per thread (ds_read_b128 on s_cw2)
        for (int e = t; e < CB * 25 * 32; e += 256) {
            int i = e >> 5, j4 = (e & 31) * 4;
            int g = i / 25, ii = i % 25;
            if (ii < s_nn[g]) {
                float4 a = *(const float4*)(cb2 + j4);
                const float* h1r = &s_h1[i * 64];
                #pragma unroll
                for (int k = 0; k < 64; ++k) {
                    float hv = h1r[k];
                    float4 wv = *(const float4*)(s_cw2 + k * 128 + j4);
                    a.x += hv * wv.x; a.y += hv * wv.y; a.z += hv * wv.z; a.w += hv * wv.w;
                }
                ushort4 o;
                o.x = f2bf(a.x); o.y = f2bf(a.y); o.z = f2bf(a.z); o.w = f2bf(a.w);
                *(ushort4*)&h_c[(size_t)(s_off[g] + ii) * 128 + j4] = o;
            }
        }
        return;
    }

    if (bid < 1312) {
        // ---- weight transpose tile: dst[n][k] = src[k][n], lds[64][65]
        const int u0 = bid - 1024;
        const float* src; short* dst;
        int srcN, nmax, dstK, n0, k0;
        if (u0 < 32) {             // lw1t [512][256] <- lw1 [256][512]
            int tn = u0 >> 2, tk = u0 & 3;
            src = lw1; srcN = 512; nmax = 512; dst = lw1t; dstK = 256;
            n0 = tn * 64; k0 = tk * 64;
        } else if (u0 < 160) {     // lw2t [1024][512] <- lw2 [512][1024]
            int u = u0 - 32; int tn = u >> 3, tk = u & 7;
            src = lw2; srcN = 1024; nmax = 1024; dst = lw2t; dstK = 512;
            n0 = tn * 64; k0 = tk * 64;
        } else {                   // fwt [512][1024] <- fw [1024][511] (row 511 = 0)
            int u = u0 - 160; int tn = u >> 4, tk = u & 15;
            src = fw; srcN = 511; nmax = 511; dst = fwt; dstK = 1024;
            n0 = tn * 64; k0 = tk * 64;
        }
        float* lds = (float*)pmem;      // 64*65*4 = 16640 B
        for (int e = t; e < 4096; e += 256) {
            int r = e >> 6, c = e & 63;
            int n = n0 + c;
            lds[r * 65 + c] = (n < nmax) ? src[(size_t)(k0 + r) * srcN + n] : 0.0f;
        }
        __syncthreads();
        for (int e = t; e < 1024; e += 256) {
            int rn = e >> 4, c4 = (e & 15) * 4;
            ushort4 o;
            o.x = f2bf(lds[(c4 + 0) * 65 + rn]);
            o.y = f2bf(lds[(c4 + 1) * 65 + rn]);
            o.z = f2bf(lds[(c4 + 2) * 65 + rn]);
            o.w = f2bf(lds[(c4 + 3) * 65 + rn]);
            *(ushort4*)&dst[(size_t)(n0 + rn) * dstK + k0 + c4] = o;
        }
        return;
    }

    if (bid == 1312) {
        // ---- global exclusive prefix sum of nfpc[4096] -> scanv, header
        int* s = (int*)pmem;
        int loc[16]; int sum = 0;
        #pragma unroll
        for (int i = 0; i < 16; ++i) { loc[i] = sum; sum += nfpc[t * 16 + i]; }
        s[t] = sum;
        __syncthreads();
        for (int d = 1; d < 256; d <<= 1) {
            int v = (t >= d) ? s[t - d] : 0;
            __syncthreads();
            s[t] += v;
            __syncthreads();
        }
        int excl = (t == 0) ? 0 : s[t - 1];
        #pragma unroll
        for (int i = 0; i < 16; ++i) scanv[t * 16 + i] = excl + loc[i];
        if (t == 255) {
            int M = s[255];
            scanv[4096] = M;
            header[0] = M;
            header[1] = (M + 127) & ~127;
        }
        return;
    }

    // ---- rowmap + zeropad, self-derived full scan in LDS (validated R12)
    {
        int* s_scan = (int*)pmem;                 // [4097]
        int* s_red  = (int*)(pmem + 16400);       // [256]
        int loc[16]; int sum = 0;
        #pragma unroll
        for (int i = 0; i < 16; ++i) { loc[i] = sum; sum += nfpc[t * 16 + i]; }
        s_red[t] = sum;
        __syncthreads();
        for (int d = 1; d < 256; d <<= 1) {
            int v = (t >= d) ? s_red[t - d] : 0;
            __syncthreads();
            s_red[t] += v;
            __syncthreads();
        }
        int excl = (t == 0) ? 0 : s_red[t - 1];
        #pragma unroll
        for (int i = 0; i < 16; ++i) s_scan[t * 16 + i] = excl + loc[i];
        if (t == 255) s_scan[4096] = s_red[255];
        __syncthreads();

        const int Mc = s_scan[4096];
        const int Mcp = (Mc + 127) & ~127;
        int r = (bid - 1313) * 256 + t;           // covers 102400
        if (r >= 102400) return;
        if (r >= Mc) {
            rm_b[r] = -1; rm_next[r] = r;
            if (r < Mcp) {
                ushort4 z = {0, 0, 0, 0};
                #pragma unroll
                for (int j = 0; j < 128; j += 4)
                    *(ushort4*)&h_c[(size_t)r * 128 + j] = z;
            }
            return;
        }
        int lo = 0, hi = 4096;
        while (hi - lo > 1) { int mid = (lo + hi) >> 1; if (s_scan[mid] <= r) lo = mid; else hi = mid; }
        int b = lo, ii = r - s_scan[b], n = s_scan[b + 1] - s_scan[b];
        rm_b[r] = b;
        rm_next[r] = (ii + 1 == n) ? s_scan[b] : r + 1;
    }
}

// ---------------- gemm1: pair(gathered from h_c) @ lw1t^T -> relu+lb1 -> hid ----------
// R8 config: BK=64, 33.8KB LDS, (256,4) — measured local optimum.
__global__ __launch_bounds__(256, 4) void gemm1_kernel(
    const unsigned short* __restrict__ h_c,   // [M_cp][128]
    const short* __restrict__ lw1t,           // [512][256]
    const float* __restrict__ lb1,
    const int* __restrict__ rm_next,
    const int* __restrict__ header,
    unsigned short* __restrict__ hid,         // [crows][512] chunk-local
    int row0, int pm)
{
    __shared__ __align__(16) char smem[33280];   // K-loop: A(16K)+B(16K); epilogue: f32[64][130]
    __shared__ int s_next[128];

    const int Mcp = header[1];
    int rem = Mcp - row0;
    int apm = (rem <= 0) ? 0 : min(pm, (rem + 127) >> 7);
    int pr, pc;
    if (!tile_assign(blockIdx.x, apm, 2, pr, pc)) return;
    const int Rl = pr * 128;                          // chunk-local
    const int R = row0 + Rl;                          // global compact row base

    const int t = threadIdx.x;
    const int w = t >> 6, l = t & 63, q = l >> 4, ln = l & 15;
    const int wr = w >> 1, wc = w & 1;
    char* ldsA = smem;
    char* ldsB = smem + 16384;

    if (t < 128) s_next[t] = rm_next[R + t];
    __syncthreads();

    f32x4 acc[4][4];
    #pragma unroll
    for (int m = 0; m < 4; ++m)
        #pragma unroll
        for (int n = 0; n < 4; ++n) acc[m][n] = 0;

    #pragma unroll
    for (int kt = 0; kt < 4; ++kt) {
        const int k0 = kt * 64;
        // ---- stage A: gather pair rows (pre-swizzled source)
        #pragma unroll
        for (int i = 0; i < 4; ++i) {
            int o = i * 4096 + t * 16;
            int row = o >> 7, colb = o & 127;
            int colb2 = colb ^ ((row & 7) << 4);
            int k = k0 + (colb2 >> 1);                // 0..255 (compile-time half per kt)
            int srow, kk2;
            if (k < 128) { srow = R + row; kk2 = k; }
            else { srow = s_next[row]; kk2 = k - 128; }
            gload16(h_c + (size_t)srow * 128 + kk2, ldsA + o);
        }
        // ---- stage B from lw1t
        #pragma unroll
        for (int i = 0; i < 4; ++i) {
            int o = i * 4096 + t * 16;
            int row = o >> 7, colb = o & 127;
            int colb2 = colb ^ ((row & 7) << 4);
            gload16(lw1t + (size_t)(pc * 128 + row) * 256 + k0 + (colb2 >> 1), ldsB + o);
        }
        asm volatile("s_waitcnt vmcnt(0)");
        __syncthreads();
        #pragma unroll
        for (int kk = 0; kk < 2; ++kk) {
            bf16x8 af[4], bf[4];
            #pragma unroll
            for (int m = 0; m < 4; ++m) {
                int row = wr * 64 + m * 16 + ln;
                int off = (row * 128 + kk * 64 + q * 16) ^ ((row & 7) << 4);
                af[m] = *(const bf16x8*)(ldsA + off);
            }
            #pragma unroll
            for (int n = 0; n < 4; ++n) {
                int row = wc * 64 + n * 16 + ln;
                int off = (row * 128 + kk * 64 + q * 16) ^ ((row & 7) << 4);
                bf[n] = *(const bf16x8*)(ldsB + off);
            }
            #pragma unroll
            for (int m = 0; m < 4; ++m)
                #pragma unroll
                for (int n = 0; n < 4; ++n)
                    acc[m][n] = MFMA16(af[m], bf[n], acc[m][n]);
        }
        __syncthreads();
    }

    // ---- epilogue: relu+bias -> stage 64-row halves to LDS f32 -> vectorized bf16 write.
    float* s_f32 = (float*)smem;        // [64][130]
    const int erow = t >> 2;            // 0..63
    const int ecl = (t & 3) * 8;        // col base; +j*32 per store
    #pragma unroll 1
    for (int h = 0; h < 2; ++h) {
        if (wr == h) {
            #pragma unroll
            for (int n = 0; n < 4; ++n) {
                int col = wc * 64 + n * 16 + ln;          // tile-local
                float bias = lb1[pc * 128 + col];
                #pragma unroll
                for (int m = 0; m < 4; ++m)
                    #pragma unroll
                    for (int r = 0; r < 4; ++r)
                        s_f32[(m * 16 + q * 4 + r) * 130 + col] =
                            fmaxf(acc[m][n][r] + bias, 0.f);
            }
        }
        __syncthreads();
        {
            const size_t gr = (size_t)(Rl + h * 64 + erow) * 512 + pc * 128;
            #pragma unroll
            for (int j = 0; j < 4; ++j) {
                int c0 = ecl + j * 32;
                float4 a = *(const float4*)&s_f32[erow * 130 + c0];
                float4 b = *(const float4*)&s_f32[erow * 130 + c0 + 4];
                u16x8 o;
                o[0] = f2bf(a.x); o[1] = f2bf(a.y); o[2] = f2bf(a.z); o[3] = f2bf(a.w);
                o[4] = f2bf(b.x); o[5] = f2bf(b.y); o[6] = f2bf(b.z); o[7] = f2bf(b.w);
                *(u16x8*)&hid[gr + c0] = o;
            }
        }
        __syncthreads();
    }
}

// ---------------- gemm2: hid @ lw2t^T + segmented maxpool -> scratch partials ----------
// R8 config: BK=64, 33.8KB LDS, (256,4).
__global__ __launch_bounds__(256, 4) void gemm2_kernel(
    const unsigned short* __restrict__ hid,   // [crows][512] chunk-local
    const short* __restrict__ lw2t,           // [1024][512]
    const int* __restrict__ rm_b,
    const int* __restrict__ scanv,
    const int* __restrict__ header,
    float* __restrict__ scratch,              // [4096][2][1024] f32
    int row0, int pm)
{
    __shared__ __align__(16) char smem[33280];   // K-loop: A(16K)+B(16K); epilogue: f32[64][130]
    __shared__ int s_batch[128];

    const int Mcp = header[1];
    int rem = Mcp - row0;
    int apm = (rem <= 0) ? 0 : min(pm, (rem + 127) >> 7);
    int pr, pc;
    if (!tile_assign(blockIdx.x, apm, 3, pr, pc)) return;
    const int Rl = pr * 128;
    const int R = row0 + Rl;

    const int t = threadIdx.x;
    const int w = t >> 6, l = t & 63, q = l >> 4, ln = l & 15;
    const int wr = w >> 1, wc = w & 1;
    char* ldsA = smem;
    char* ldsB = smem + 16384;

    if (t < 128) s_batch[t] = rm_b[R + t];
    __syncthreads();

    f32x4 acc[4][4];
    #pragma unroll
    for (int m = 0; m < 4; ++m)
        #pragma unroll
        for (int n = 0; n < 4; ++n) acc[m][n] = 0;

    for (int kt = 0; kt < 8; ++kt) {
        const int k0 = kt * 64;
        #pragma unroll
        for (int i = 0; i < 4; ++i) {
            int o = i * 4096 + t * 16;
            int row = o >> 7, colb = o & 127;
            int colb2 = colb ^ ((row & 7) << 4);
            gload16(hid + (size_t)(Rl + row) * 512 + k0 + (colb2 >> 1), ldsA + o);
        }
        #pragma unroll
        for (int i = 0; i < 4; ++i) {
            int o = i * 4096 + t * 16;
            int row = o >> 7, colb = o & 127;
            int colb2 = colb ^ ((row & 7) << 4);
            gload16(lw2t + (size_t)(pc * 128 + row) * 512 + k0 + (colb2 >> 1), ldsB + o);
        }
        asm volatile("s_waitcnt vmcnt(0)");
        __syncthreads();
        #pragma unroll
        for (int kk = 0; kk < 2; ++kk) {
            bf16x8 af[4], bf[4];
            #pragma unroll
            for (int m = 0; m < 4; ++m) {
                int row = wr * 64 + m * 16 + ln;
                int off = (row * 128 + kk * 64 + q * 16) ^ ((row & 7) << 4);
                af[m] = *(const bf16x8*)(ldsA + off);
            }
            #pragma unroll
            for (int n = 0; n < 4; ++n) {
                int row = wc * 64 + n * 16 + ln;
                int off = (row * 128 + kk * 64 + q * 16) ^ ((row & 7) << 4);
                bf[n] = *(const bf16x8*)(ldsB + off);
            }
            #pragma unroll
            for (int m = 0; m < 4; ++m)
                #pragma unroll
                for (int n = 0; n < 4; ++n)
                    acc[m][n] = MFMA16(af[m], bf[n], acc[m][n]);
        }
        __syncthreads();
    }

    // ---- segmented maxpool epilogue: stage 64-row halves, walk 32-row units.
    // A batch (n<=25<32) spans at most 2 consecutive 32-row units ->
    // slot = (batch started before this unit) ? 1 : 0.
    // s_f32 holds only the current 64-row HALF: index half-local (esub*32+row).
    float* s_f32 = (float*)smem;    // [64][130] f32
    const int ecol = t & 127, esub = t >> 7;     // 256 threads: 128 cols x 2 units
    #pragma unroll 1
    for (int h = 0; h < 2; ++h) {
        if (wr == h) {
            #pragma unroll
            for (int m = 0; m < 4; ++m)
                #pragma unroll
                for (int n = 0; n < 4; ++n)
                    #pragma unroll
                    for (int r = 0; r < 4; ++r)
                        s_f32[(m * 16 + q * 4 + r) * 130 + wc * 64 + n * 16 + ln] = acc[m][n][r];
        }
        __syncthreads();
        {
            const int ub = R + h * 64 + esub * 32;   // unit base (global row)
            const int rb = h * 64 + esub * 32;       // tile-local base (s_batch index)
            const int lb = esub * 32;                // half-local base (s_f32 index)
            int curb = s_batch[rb];
            float curmax = s_f32[lb * 130 + ecol];
            #pragma unroll 8
            for (int row = 1; row < 32; ++row) {
                int b = s_batch[rb + row];
                float v = s_f32[(lb + row) * 130 + ecol];
                if (b == curb) {
                    curmax = fmaxf(curmax, v);
                } else {
                    if (curb >= 0) {
                        int slot = (scanv[curb] < ub) ? 1 : 0;
                        scratch[((size_t)curb * 2 + slot) * 1024 + pc * 128 + ecol] = curmax;
                    }
                    curb = b;
                    curmax = v;
                }
            }
            if (curb >= 0) {
                int slot = (scanv[curb] < ub) ? 1 : 0;
                scratch[((size_t)curb * 2 + slot) * 1024 + pc * 128 + ecol] = curmax;
            }
        }
        __syncthreads();
    }
}

// ---------------- merge: max of <=2 partials + lb2 -> pooled bf16 ----------------
__global__ void merge_kernel(const float* __restrict__ scratch, const int* __restrict__ scanv,
                             const float* __restrict__ lb2, unsigned short* __restrict__ pooled_b)
{
    const int b = blockIdx.x;                 // 4096 blocks; thread t does cols 4t..4t+3
    const int col4 = threadIdx.x * 4;
    const int o0 = scanv[b], o1 = scanv[b + 1];
    const bool spans = (o0 >> 5) != ((o1 - 1) >> 5);    // 32-row units
    float4 v = *(const float4*)&scratch[((size_t)b * 2) * 1024 + col4];
    if (spans) {
        float4 u = *(const float4*)&scratch[((size_t)b * 2 + 1) * 1024 + col4];
        v.x = fmaxf(v.x, u.x); v.y = fmaxf(v.y, u.y);
        v.z = fmaxf(v.z, u.z); v.w = fmaxf(v.w, u.w);
    }
    float4 bb = *(const float4*)(lb2 + col4);
    ushort4 o;
    o.x = f2bf(v.x + bb.x); o.y = f2bf(v.y + bb.y);
    o.z = f2bf(v.z + bb.z); o.w = f2bf(v.w + bb.w);
    *(ushort4*)&pooled_b[(size_t)b * 1024 + col4] = o;
}

// ---------------- final: pooled[4096,1024] @ fw[1024,511] + fb ----------------
__global__ __launch_bounds__(512, 2) void final_kernel(
    const unsigned short* __restrict__ pooled_b,
    const short* __restrict__ fwt,    // bf16 [512][1024]
    const float* __restrict__ fb,
    float* __restrict__ out)
{
    const int tid = threadIdx.x;
    const int w = tid >> 6, l = tid & 63, q = l >> 4, ln = l & 15;
    const int rb = blockIdx.x * 128 + w * 16;
    const int nb0 = blockIdx.y * 64;

    f32x4 acc[4];
    #pragma unroll
    for (int j = 0; j < 4; ++j) acc[j] = 0;

    const short* pb = (const short*)pooled_b;
    #pragma unroll 4
    for (int ks = 0; ks < 32; ++ks) {
        bf16x8 a = *(const bf16x8*)(pb + (rb + ln) * 1024 + ks * 32 + q * 8);
        #pragma unroll
        for (int j = 0; j < 4; ++j) {
            bf16x8 bf = *(const bf16x8*)(fwt + (nb0 + j * 16 + ln) * 1024 + ks * 32 + q * 8);
            acc[j] = MFMA16(a, bf, acc[j]);
        }
    }
    #pragma unroll
    for (int j = 0; j < 4; ++j) {
        int col = nb0 + j * 16 + ln;
        if (col < 511) {
            float bias = fb[col];
            #pragma unroll
            for (int r = 0; r < 4; ++r) {
                int row = rb + q * 4 + r;
                out[row * 511 + col] = acc[j][r] + bias;
            }
        }
    }
}

extern "C" void kernel_launch(void* const* d_in, const int* in_sizes, int n_in,
                              void* d_out, int out_size, void* d_ws, size_t ws_size,
                              hipStream_t stream)
{
    const float* fpoc = (const float*)d_in[0];
    const float* cw1  = (const float*)d_in[1];
    const float* cb1  = (const float*)d_in[2];
    const float* cw2  = (const float*)d_in[3];
    const float* cb2  = (const float*)d_in[4];
    const float* lw1  = (const float*)d_in[5];
    const float* lb1  = (const float*)d_in[6];
    const float* lw2  = (const float*)d_in[7];
    const float* lb2  = (const float*)d_in[8];
    const float* fw   = (const float*)d_in[9];
    const float* fb   = (const float*)d_in[10];
    const int*  nfpc  = (const int*)d_in[11];

    char* ws = (char*)d_ws;
    unsigned short* pooled_b = (unsigned short*)(ws + WS_POOLED);
    short* lw1t   = (short*)(ws + WS_LW1T);
    short* lw2t   = (short*)(ws + WS_LW2T);
    short* fwt    = (short*)(ws + WS_FWT);
    int*   scanv  = (int*)(ws + WS_SCAN);
    int*   header = (int*)(ws + WS_HEADER);
    int*   rm_b   = (int*)(ws + WS_RMB);
    int*   rm_next= (int*)(ws + WS_RMNEXT);
    unsigned short* h_c = (unsigned short*)(ws + WS_HC);
    float* scratch = (float*)(ws + WS_SCRATCH);
    unsigned short* hid = (unsigned short*)(ws + WS_HID);

    // adaptive chunking of hid (worst case 102400 rows x 512 x bf16 = 100 MB)
    size_t avail = (ws_size > WS_HID) ? ws_size - WS_HID : 0;
    int n_chunks = 1;
    while (n_chunks < 16 && (size_t)(104857600u / n_chunks) > avail) n_chunks <<= 1;
    const int crows = 102400 / n_chunks;
    const int pm = crows / 128;

    hipLaunchKernelGGL(prep_kernel, dim3(1713), dim3(256), 0, stream,
                       lw1, lw2, fw, lw1t, lw2t, fwt, nfpc, scanv, header,
                       fpoc, cw1, cb1, cw2, cb2, rm_b, rm_next, h_c);
    const int g1 = ((pm * 4 + 7) / 8) * 8;   // grid covers worst-case per-XCD share
    const int g2 = pm * 8;
    for (int c = 0; c < n_chunks; ++c) {
        int row0 = c * crows;
        hipLaunchKernelGGL(gemm1_kernel, dim3(g1), dim3(256), 0, stream,
                           h_c, lw1t, lb1, rm_next, header, hid, row0, pm);
        hipLaunchKernelGGL(gemm2_kernel, dim3(g2), dim3(256), 0, stream,
                           hid, lw2t, rm_b, scanv, header, scratch, row0, pm);
    }
    hipLaunchKernelGGL(merge_kernel, dim3(4096), dim3(256), 0, stream,
                       scratch, scanv, lb2, pooled_b);
    hipLaunchKernelGGL(final_kernel, dim3(32, 8), dim3(512), 0, stream,
                       pooled_b, fwt, fb, (float*)d_out);
}